// Round 12
// baseline (493.686 us; speedup 1.0000x reference)
//
#include <hip/hip_runtime.h>
#include <hip/hip_bf16.h>
#include <math.h>

typedef __bf16 bf16;
typedef __bf16 bf16x8 __attribute__((ext_vector_type(8)));
typedef __bf16 bf16x4 __attribute__((ext_vector_type(4)));
typedef float f32x4 __attribute__((ext_vector_type(4)));

#define NTOK 65536
#define DMODEL 256

// async global->LDS, 16B per lane; LDS dest = wave-uniform base + lane*16
#define GL16(g, l) __builtin_amdgcn_global_load_lds( \
    (const __attribute__((address_space(1))) void*)(g), \
    (__attribute__((address_space(3))) void*)(l), 16, 0, 0)

// window-order token m -> global token g (the _reverse mapping)
__device__ __forceinline__ int unwin_idx(int m) {
    int widx = m >> 6, t = m & 63;
    int b = widx >> 6, wl = widx & 63;
    return (b << 12) | (((wl >> 3) * 8 + (t >> 3)) << 6) | ((wl & 7) * 8 + (t & 7));
}

__device__ __forceinline__ float gelu_fast(float x) {
    float z = 0.7978845608f * (x + 0.044715f * x * x * x);
    float e = __expf(2.f * z);
    float t = (e - 1.f) / (e + 1.f);
    return 0.5f * x * (1.f + t);
}

// ---------------------------------------------------------------------------
// weight convert (round-5 verbatim)
// ---------------------------------------------------------------------------
__global__ __launch_bounds__(256)
void cvt8(const float* __restrict__ s0, const float* __restrict__ s1,
          const float* __restrict__ s2, const float* __restrict__ s3,
          const float* __restrict__ s4, const float* __restrict__ s5,
          const float* __restrict__ s6, const float* __restrict__ s7,
          bf16* __restrict__ d)
{
    int idx = (blockIdx.x * 256 + threadIdx.x) * 4;
    const float* s; int off;
    if      (idx < 196608) { s = s0; off = 0; }
    else if (idx < 262144) { s = s1; off = 196608; }
    else if (idx < 393216) { s = s2; off = 262144; }
    else if (idx < 524288) { s = s3; off = 393216; }
    else if (idx < 720896) { s = s4; off = 524288; }
    else if (idx < 786432) { s = s5; off = 720896; }
    else if (idx < 917504) { s = s6; off = 786432; }
    else                   { s = s7; off = 917504; }
    float4 v = *reinterpret_cast<const float4*>(s + (idx - off));
    bf16x4 o; o[0] = (bf16)v.x; o[1] = (bf16)v.y; o[2] = (bf16)v.z; o[3] = (bf16)v.w;
    *reinterpret_cast<bf16x4*>(d + idx) = o;
}

// ---------------------------------------------------------------------------
// QKV GEMM with FUSED window-partition + PE (prep_win eliminated).
// A: reg-staged fp32 feat+pe -> bf16 -> padded LDS As[2][128][40]
//    (round-3 proven staging on the round-5 proven 2-phase skeleton).
// B: GL16 linear (round-5 verbatim).
// Epilogue seg0/1: LDS-transpose coalesced stores (round-11 proven);
// seg2 (V): round-5 vectored transposed store, verbatim.
// grid 6144 = 8 XCD chunks of 768; decode identical to round-5 qkv2.
// ---------------------------------------------------------------------------
__global__ __launch_bounds__(256, 4)
void gemm_qkvf(const float* __restrict__ feat_A, const float* __restrict__ feat_B,
               const float* __restrict__ pe,
               const bf16* __restrict__ wA, const bf16* __restrict__ wB,
               const float* __restrict__ bA, const float* __restrict__ bB,
               bf16* __restrict__ qA, bf16* __restrict__ kA, bf16* __restrict__ vA,
               bf16* __restrict__ qB, bf16* __restrict__ kB, bf16* __restrict__ vB)
{
    __shared__ bf16 lds[18432];      // As[2][128][40]=10240 | Bs[2][4096]=8192 ; epilogue reuses [0..17407]
    bf16* As = lds;                  // As[buf] at buf*5120, row stride 40 (pad kills conflicts)
    bf16* Bs = lds + 10240;          // Bs[buf] at buf*4096, linear (GL16 dest)
    const int tid = threadIdx.x;
    const int bx = blockIdx.x;
    const int xcd = bx & 7, slot = bx >> 3;
    const int L = xcd * 768 + slot;
    const int mt = L / 6, nb = L - mt * 6;
    const int pass = mt >> 9, mb = mt & 511;
    const int seg = nb >> 1, nl0 = (nb & 1) * 128;
    const int m0 = mb * 128;

    const float* feat = pass ? feat_B : feat_A;
    const bf16* Wf = (seg == 0) ? (pass ? wB : wA) : (pass ? wA : wB);
    const float* Bf = (seg == 0) ? (pass ? bB : bA) : (pass ? bA : bB);
    const bf16* W = Wf + (size_t)seg * 65536;
    const float* bia = Bf + seg * 256;
    bf16* qout = pass ? qB : qA;
    bf16* kout = pass ? kA : kB;
    bf16* vout = pass ? vA : vB;

    const int lane = tid & 63, w = tid >> 6;
    const int wr = w >> 1, wc = w & 1;
    const int lr = lane & 15, lg = lane >> 4;
    const int srow = tid >> 2, scol = (tid & 3) * 8;   // B staging (GL16)
    const int r = tid >> 1, cs = (tid & 1) * 16;       // A staging (16 elems/thread)

    const int mrow = m0 + r;
    const int tA = mrow & 63;
    const int gA = unwin_idx(mrow);
    const float* fsrc = feat + (size_t)gA * DMODEL + cs;
    const float* psrc = pe + tA * DMODEL + cs;

    const bf16* Bg = W + (size_t)(nl0 + srow) * 256 + scol;

    f32x4 acc[4][4];
    const f32x4 zero = {0.f, 0.f, 0.f, 0.f};
#pragma unroll
    for (int mi = 0; mi < 4; ++mi)
#pragma unroll
        for (int nj = 0; nj < 4; ++nj) acc[mi][nj] = zero;

    auto stageB = [&](int buf, int k0) {
        GL16(Bg + k0, &Bs[buf * 4096 + tid * 8]);
        GL16(Bg + 64 * 256 + k0, &Bs[buf * 4096 + 2048 + tid * 8]);
    };
    auto stageA = [&](int buf, int k0) {
        const float4* fs = reinterpret_cast<const float4*>(fsrc + k0);
        const float4* ps = reinterpret_cast<const float4*>(psrc + k0);
        bf16* dst = &As[buf * 5120 + r * 40 + cs];
#pragma unroll
        for (int q = 0; q < 4; ++q) {
            float4 a = fs[q], p = ps[q];
            dst[q * 4 + 0] = (bf16)(a.x + p.x);
            dst[q * 4 + 1] = (bf16)(a.y + p.y);
            dst[q * 4 + 2] = (bf16)(a.z + p.z);
            dst[q * 4 + 3] = (bf16)(a.w + p.w);
        }
    };
    auto compute = [&](int buf) {
        bf16x8 af[4], bfr[4];
#pragma unroll
        for (int mi = 0; mi < 4; ++mi)
            af[mi] = *reinterpret_cast<const bf16x8*>(&As[buf * 5120 + (wr * 64 + mi * 16 + lr) * 40 + lg * 8]);
#pragma unroll
        for (int nj = 0; nj < 4; ++nj)
            bfr[nj] = *reinterpret_cast<const bf16x8*>(&Bs[buf * 4096 + (wc * 64 + nj * 16 + lr) * 32 + lg * 8]);
#pragma unroll
        for (int mi = 0; mi < 4; ++mi)
#pragma unroll
            for (int nj = 0; nj < 4; ++nj)
                acc[mi][nj] = __builtin_amdgcn_mfma_f32_16x16x32_bf16(af[mi], bfr[nj], acc[mi][nj], 0, 0, 0);
    };

    stageB(0, 0);
    stageA(0, 0);
    __syncthreads();
#pragma unroll
    for (int t = 0; t < 7; ++t) {
        stageB((t + 1) & 1, (t + 1) * 32);   // async, flies under compute
        stageA((t + 1) & 1, (t + 1) * 32);   // reg-staged; compiler schedules loads early
        compute(t & 1);
        __syncthreads();
    }
    compute(1);

    if (seg == 2) {
        const int widx = mb * 2 + wr;
#pragma unroll
        for (int nj = 0; nj < 4; ++nj) {
            int cl = nl0 + wc * 64 + nj * 16 + lr;
            float bv = bia[cl];
#pragma unroll
            for (int mi = 0; mi < 4; ++mi) {
                bf16x4 o;
#pragma unroll
                for (int i = 0; i < 4; ++i) o[i] = (bf16)(acc[mi][nj][i] + bv);
                *reinterpret_cast<bf16x4*>(vout + ((size_t)widx * 256 + cl) * 64 + mi * 16 + lg * 4) = o;
            }
        }
    } else {
        bf16* out = (seg == 0) ? qout : kout;
        // LDS-transpose coalesced epilogue (round-11 proven pattern)
        __syncthreads();
#pragma unroll
        for (int nj = 0; nj < 4; ++nj) {
            int coll = wc * 64 + nj * 16 + lr;
            float bv = bia[nl0 + coll];
#pragma unroll
            for (int mi = 0; mi < 4; ++mi)
#pragma unroll
                for (int i = 0; i < 4; ++i) {
                    int rowl = wr * 64 + mi * 16 + lg * 4 + i;
                    lds[rowl * 136 + coll] = (bf16)(acc[mi][nj][i] + bv);
                }
        }
        __syncthreads();
#pragma unroll
        for (int j = 0; j < 4; ++j) {
            int rowl = j * 32 + (tid >> 3);
#pragma unroll
            for (int h = 0; h < 2; ++h) {
                int coll = h * 64 + (tid & 7) * 8;
                *reinterpret_cast<bf16x8*>(out + (size_t)(m0 + rowl) * 256 + nl0 + coll) =
                    *reinterpret_cast<const bf16x8*>(&lds[rowl * 136 + coll]);
            }
        }
    }
}

// ---------------------------------------------------------------------------
// Merged FFN1 (round-11 PASSING version, verbatim).
// ---------------------------------------------------------------------------
__global__ __launch_bounds__(256, 4)
void gemm_gelu(const bf16* __restrict__ y1A, const bf16* __restrict__ y1B,
               const bf16* __restrict__ wA, const bf16* __restrict__ wB,
               const float* __restrict__ bA, const float* __restrict__ bB,
               bf16* __restrict__ hbA, bf16* __restrict__ hbB)
{
    __shared__ bf16 lds[17408];
    bf16* As = lds;
    bf16* Bs = lds + 8192;
    const int tid = threadIdx.x;
    const int bx = blockIdx.x;
    const int xcd = bx & 7, slot = bx >> 3;
    const int L = xcd * 512 + slot;
    const int mt = L >> 2, nb = L & 3;
    const int str = mt >> 9, mb = mt & 511;
    const int m0 = mb * 128, n0 = nb * 128;

    const bf16* A = str ? y1B : y1A;
    const bf16* W = str ? wB : wA;
    const float* bia = str ? bB : bA;
    bf16* C = str ? hbB : hbA;

    const int lane = tid & 63, w = tid >> 6;
    const int wr = w >> 1, wc = w & 1;
    const int lr = lane & 15, lg = lane >> 4;
    const int srow = tid >> 2, scol = (tid & 3) * 8;

    const bf16* Ag = A + (size_t)(m0 + srow) * 256 + scol;
    const bf16* Bg = W + (size_t)(n0 + srow) * 256 + scol;

    f32x4 acc[4][4];
    const f32x4 zero = {0.f, 0.f, 0.f, 0.f};
#pragma unroll
    for (int mi = 0; mi < 4; ++mi)
#pragma unroll
        for (int nj = 0; nj < 4; ++nj) acc[mi][nj] = zero;

    auto stage = [&](int buf, int k0) {
        GL16(Ag + k0, &As[buf * 4096 + tid * 8]);
        GL16(Ag + 64 * 256 + k0, &As[buf * 4096 + 2048 + tid * 8]);
        GL16(Bg + k0, &Bs[buf * 4096 + tid * 8]);
        GL16(Bg + 64 * 256 + k0, &Bs[buf * 4096 + 2048 + tid * 8]);
    };
    auto compute = [&](int buf) {
        bf16x8 af[4], bfr[4];
#pragma unroll
        for (int mi = 0; mi < 4; ++mi)
            af[mi] = *reinterpret_cast<const bf16x8*>(&As[buf * 4096 + (wr * 64 + mi * 16 + lr) * 32 + lg * 8]);
#pragma unroll
        for (int nj = 0; nj < 4; ++nj)
            bfr[nj] = *reinterpret_cast<const bf16x8*>(&Bs[buf * 4096 + (wc * 64 + nj * 16 + lr) * 32 + lg * 8]);
#pragma unroll
        for (int mi = 0; mi < 4; ++mi)
#pragma unroll
            for (int nj = 0; nj < 4; ++nj)
                acc[mi][nj] = __builtin_amdgcn_mfma_f32_16x16x32_bf16(af[mi], bfr[nj], acc[mi][nj], 0, 0, 0);
    };

    stage(0, 0);
    __syncthreads();
#pragma unroll
    for (int t = 0; t < 7; ++t) {
        stage((t + 1) & 1, (t + 1) * 32);
        compute(t & 1);
        __syncthreads();
    }
    compute(1);

    __syncthreads();
#pragma unroll
    for (int nj = 0; nj < 4; ++nj) {
        int coll = wc * 64 + nj * 16 + lr;
        float bv = bia[n0 + coll];
#pragma unroll
        for (int mi = 0; mi < 4; ++mi)
#pragma unroll
            for (int i = 0; i < 4; ++i) {
                int rowl = wr * 64 + mi * 16 + lg * 4 + i;
                lds[rowl * 136 + coll] = (bf16)gelu_fast(acc[mi][nj][i] + bv);
            }
    }
    __syncthreads();
#pragma unroll
    for (int j = 0; j < 4; ++j)
#pragma unroll
        for (int h = 0; h < 2; ++h) {
            int rowl = j * 32 + (tid >> 3);
            int coll = h * 64 + (tid & 7) * 8;
            *reinterpret_cast<bf16x8*>(C + (size_t)(m0 + rowl) * 512 + n0 + coll) =
                *reinterpret_cast<const bf16x8*>(&lds[rowl * 136 + coll]);
        }
}

// ---------------------------------------------------------------------------
// gemm_out (round-11 PASSING version, verbatim).
// ---------------------------------------------------------------------------
template<int WK, int UNWIN>
__global__ __launch_bounds__(256, 4)
void gemm_out(const bf16* __restrict__ A0, const bf16* __restrict__ A1,
              const bf16* __restrict__ W0, const bf16* __restrict__ W1,
              const float* __restrict__ b0, const float* __restrict__ b1,
              bf16* __restrict__ C0, bf16* __restrict__ C1)
{
    __shared__ bf16 lds[17408];
    bf16* As = lds;
    bf16* Bs = lds + 8192;
    const int tid = threadIdx.x;
    const int bx = blockIdx.x;
    const int xcd = bx & 7, slot = bx >> 3;
    const int L = xcd * 256 + slot;
    const int mt = L >> 1, nb = L & 1;
    const int str = mt >> 9, mb = mt & 511;
    const int m0 = mb * 128, n0 = nb * 128;

    const bf16* A = str ? A1 : A0;
    const bf16* W = str ? W1 : W0;
    const float* bia = str ? b1 : b0;
    bf16* C = str ? C1 : C0;

    const int lane = tid & 63, w = tid >> 6;
    const int wr = w >> 1, wc = w & 1;
    const int lr = lane & 15, lg = lane >> 4;
    const int srow = tid >> 2, scol = (tid & 3) * 8;

    const bf16* Ag = A + (size_t)(m0 + srow) * WK + scol;
    const bf16* Bg = W + (size_t)(n0 + srow) * WK + scol;

    f32x4 acc[4][4];
    const f32x4 zero = {0.f, 0.f, 0.f, 0.f};
#pragma unroll
    for (int mi = 0; mi < 4; ++mi)
#pragma unroll
        for (int nj = 0; nj < 4; ++nj) acc[mi][nj] = zero;

    auto stage = [&](int buf, int k0) {
        GL16(Ag + k0, &As[buf * 4096 + tid * 8]);
        GL16(Ag + (size_t)64 * WK + k0, &As[buf * 4096 + 2048 + tid * 8]);
        GL16(Bg + k0, &Bs[buf * 4096 + tid * 8]);
        GL16(Bg + (size_t)64 * WK + k0, &Bs[buf * 4096 + 2048 + tid * 8]);
    };
    auto compute = [&](int buf) {
        bf16x8 af[4], bfr[4];
#pragma unroll
        for (int mi = 0; mi < 4; ++mi)
            af[mi] = *reinterpret_cast<const bf16x8*>(&As[buf * 4096 + (wr * 64 + mi * 16 + lr) * 32 + lg * 8]);
#pragma unroll
        for (int nj = 0; nj < 4; ++nj)
            bfr[nj] = *reinterpret_cast<const bf16x8*>(&Bs[buf * 4096 + (wc * 64 + nj * 16 + lr) * 32 + lg * 8]);
#pragma unroll
        for (int mi = 0; mi < 4; ++mi)
#pragma unroll
            for (int nj = 0; nj < 4; ++nj)
                acc[mi][nj] = __builtin_amdgcn_mfma_f32_16x16x32_bf16(af[mi], bfr[nj], acc[mi][nj], 0, 0, 0);
    };

    const int NT = WK / 32;
    stage(0, 0);
    __syncthreads();
#pragma unroll
    for (int t = 0; t < NT - 1; ++t) {
        stage((t + 1) & 1, (t + 1) * 32);
        compute(t & 1);
        __syncthreads();
    }
    compute((NT - 1) & 1);

    __syncthreads();
#pragma unroll
    for (int nj = 0; nj < 4; ++nj) {
        int coll = wc * 64 + nj * 16 + lr;
        float bv = bia[n0 + coll];
#pragma unroll
        for (int mi = 0; mi < 4; ++mi)
#pragma unroll
            for (int i = 0; i < 4; ++i) {
                int rowl = wr * 64 + mi * 16 + lg * 4 + i;
                lds[rowl * 136 + coll] = (bf16)(acc[mi][nj][i] + bv);
            }
    }
    __syncthreads();
#pragma unroll
    for (int j = 0; j < 4; ++j) {
        int rowl = j * 32 + (tid >> 3);
        int gr = UNWIN ? unwin_idx(m0 + rowl) : (m0 + rowl);
#pragma unroll
        for (int h = 0; h < 2; ++h) {
            int coll = h * 64 + (tid & 7) * 8;
            *reinterpret_cast<bf16x8*>(C + (size_t)gr * 256 + n0 + coll) =
                *reinterpret_cast<const bf16x8*>(&lds[rowl * 136 + coll]);
        }
    }
}

// ---------------------------------------------------------------------------
// ln_fz (round-10 PASSING version, verbatim)
// ---------------------------------------------------------------------------
template<int RESF, int OUTF>
__global__ __launch_bounds__(256)
void ln_fz(const bf16* __restrict__ x0, const bf16* __restrict__ x1,
           const float* __restrict__ rf0, const float* __restrict__ rf1,
           const bf16* __restrict__ rb0, const bf16* __restrict__ rb1,
           const float* __restrict__ g0, const float* __restrict__ g1,
           const float* __restrict__ be0, const float* __restrict__ be1,
           float* __restrict__ of0, float* __restrict__ of1,
           bf16* __restrict__ ob0, bf16* __restrict__ ob1)
{
    const int bx = blockIdx.x;
    const int str = bx >> 14, b = bx & 16383;
    const bf16* x = str ? x1 : x0;
    const float* rf = str ? rf1 : rf0;
    const bf16* rb = str ? rb1 : rb0;
    const float* gamma = str ? g1 : g0;
    const float* beta = str ? be1 : be0;
    float* outf = str ? of1 : of0;
    bf16* outb = str ? ob1 : ob0;

    int row = b * 4 + (threadIdx.x >> 6);
    int lane = threadIdx.x & 63;
    size_t base = (size_t)row * 256 + lane * 4;
    bf16x4 xv = *reinterpret_cast<const bf16x4*>(x + base);
    float v[4];
    if (RESF) {
        float4 rv = *reinterpret_cast<const float4*>(rf + base);
        v[0] = rv.x + (float)xv[0];
        v[1] = rv.y + (float)xv[1];
        v[2] = rv.z + (float)xv[2];
        v[3] = rv.w + (float)xv[3];
    } else {
        bf16x4 rv = *reinterpret_cast<const bf16x4*>(rb + base);
        v[0] = (float)rv[0] + (float)xv[0];
        v[1] = (float)rv[1] + (float)xv[1];
        v[2] = (float)rv[2] + (float)xv[2];
        v[3] = (float)rv[3] + (float)xv[3];
    }
    float s = v[0] + v[1] + v[2] + v[3];
    float q = v[0] * v[0] + v[1] * v[1] + v[2] * v[2] + v[3] * v[3];
#pragma unroll
    for (int m = 1; m < 64; m <<= 1) {
        s += __shfl_xor(s, m);
        q += __shfl_xor(q, m);
    }
    float mean = s * (1.f / 256.f);
    float var = q * (1.f / 256.f) - mean * mean;
    float rstd = rsqrtf(var + 1e-5f);
    float4 gv = *reinterpret_cast<const float4*>(gamma + lane * 4);
    float4 bv = *reinterpret_cast<const float4*>(beta + lane * 4);
    float o[4];
    o[0] = (v[0] - mean) * rstd * gv.x + bv.x;
    o[1] = (v[1] - mean) * rstd * gv.y + bv.y;
    o[2] = (v[2] - mean) * rstd * gv.z + bv.z;
    o[3] = (v[3] - mean) * rstd * gv.w + bv.w;
    if (OUTF) {
        float4 ov; ov.x = o[0]; ov.y = o[1]; ov.z = o[2]; ov.w = o[3];
        *reinterpret_cast<float4*>(outf + base) = ov;
    } else {
        bf16x4 ob;
        ob[0] = (bf16)o[0]; ob[1] = (bf16)o[1]; ob[2] = (bf16)o[2]; ob[3] = (bf16)o[3];
        *reinterpret_cast<bf16x4*>(outb + base) = ob;
    }
}

// ---------------------------------------------------------------------------
// Merged attention (round-5 PASSING version, verbatim).
// ---------------------------------------------------------------------------
__global__ __launch_bounds__(256)
void attn_win2(const bf16* qA, const bf16* __restrict__ kA,
               const bf16* __restrict__ vA,
               const bf16* qB, const bf16* __restrict__ kB,
               const bf16* __restrict__ vB)
{
    __shared__ bf16 Ps[4][64][72];
    const int tid = threadIdx.x;
    const int wv = tid >> 6, lane = tid & 63;
    const int str = blockIdx.x >> 10, widx = blockIdx.x & 1023, head = wv;
    const int lr = lane & 15, lg = lane >> 4;
    const bf16* qbuf = str ? qB : qA;
    const bf16* kbuf = str ? kB : kA;
    const bf16* vtbuf = str ? vB : vA;
    bf16* obuf = const_cast<bf16*>(qbuf);
    const bf16* qb = qbuf + (size_t)widx * 64 * 256 + head * 64;
    const bf16* kb = kbuf + (size_t)widx * 64 * 256 + head * 64;
    const bf16* vb = vtbuf + (size_t)widx * 16384 + head * 64 * 64;

    const f32x4 zero = {0.f, 0.f, 0.f, 0.f};
    f32x4 sacc[4][4];
#pragma unroll
    for (int mi = 0; mi < 4; ++mi)
#pragma unroll
        for (int nj = 0; nj < 4; ++nj) sacc[mi][nj] = zero;

#pragma unroll
    for (int k0 = 0; k0 < 64; k0 += 32) {
        bf16x8 af[4], bfr[4];
#pragma unroll
        for (int mi = 0; mi < 4; ++mi)
            af[mi] = *reinterpret_cast<const bf16x8*>(qb + (size_t)(mi * 16 + lr) * 256 + k0 + lg * 8);
#pragma unroll
        for (int nj = 0; nj < 4; ++nj)
            bfr[nj] = *reinterpret_cast<const bf16x8*>(kb + (size_t)(nj * 16 + lr) * 256 + k0 + lg * 8);
#pragma unroll
        for (int mi = 0; mi < 4; ++mi)
#pragma unroll
            for (int nj = 0; nj < 4; ++nj)
                sacc[mi][nj] = __builtin_amdgcn_mfma_f32_16x16x32_bf16(af[mi], bfr[nj], sacc[mi][nj], 0, 0, 0);
    }

    const float c = 0.125f * 1.4426950408889634f;  // log2(e)/sqrt(dh)
    float rsum[4][4];
#pragma unroll
    for (int mi = 0; mi < 4; ++mi)
#pragma unroll
        for (int i = 0; i < 4; ++i) {
            float m = fmaxf(fmaxf(sacc[mi][0][i], sacc[mi][1][i]), fmaxf(sacc[mi][2][i], sacc[mi][3][i]));
            m = fmaxf(m, __shfl_xor(m, 1));
            m = fmaxf(m, __shfl_xor(m, 2));
            m = fmaxf(m, __shfl_xor(m, 4));
            m = fmaxf(m, __shfl_xor(m, 8));
#pragma unroll
            for (int nj = 0; nj < 4; ++nj)
                sacc[mi][nj][i] = exp2f((sacc[mi][nj][i] - m) * c);
            float s = sacc[mi][0][i] + sacc[mi][1][i] + sacc[mi][2][i] + sacc[mi][3][i];
            s += __shfl_xor(s, 1);
            s += __shfl_xor(s, 2);
            s += __shfl_xor(s, 4);
            s += __shfl_xor(s, 8);
            rsum[mi][i] = s;
        }

#pragma unroll
    for (int mi = 0; mi < 4; ++mi)
#pragma unroll
        for (int nj = 0; nj < 4; ++nj)
#pragma unroll
            for (int i = 0; i < 4; ++i)
                Ps[wv][mi * 16 + lg * 4 + i][nj * 16 + lr] = (bf16)sacc[mi][nj][i];

    f32x4 oacc[4][4];
#pragma unroll
    for (int mi = 0; mi < 4; ++mi)
#pragma unroll
        for (int nj = 0; nj < 4; ++nj) oacc[mi][nj] = zero;
#pragma unroll
    for (int k0 = 0; k0 < 64; k0 += 32) {
        bf16x8 af[4], bfr[4];
#pragma unroll
        for (int mi = 0; mi < 4; ++mi)
            af[mi] = *reinterpret_cast<const bf16x8*>(&Ps[wv][mi * 16 + lr][k0 + lg * 8]);
#pragma unroll
        for (int nj = 0; nj < 4; ++nj)
            bfr[nj] = *reinterpret_cast<const bf16x8*>(vb + (size_t)(nj * 16 + lr) * 64 + k0 + lg * 8);
#pragma unroll
        for (int mi = 0; mi < 4; ++mi)
#pragma unroll
            for (int nj = 0; nj < 4; ++nj)
                oacc[mi][nj] = __builtin_amdgcn_mfma_f32_16x16x32_bf16(af[mi], bfr[nj], oacc[mi][nj], 0, 0, 0);
    }
#pragma unroll
    for (int mi = 0; mi < 4; ++mi)
#pragma unroll
        for (int i = 0; i < 4; ++i) {
            float inv = 1.0f / rsum[mi][i];
            int row = mi * 16 + lg * 4 + i;
#pragma unroll
            for (int nj = 0; nj < 4; ++nj)
                obuf[((size_t)widx * 64 + row) * 256 + head * 64 + nj * 16 + lr] =
                    (bf16)(oacc[mi][nj][i] * inv);
        }
}

extern "C" void kernel_launch(void* const* d_in, const int* in_sizes, int n_in,
                              void* d_out, int out_size, void* d_ws, size_t ws_size,
                              hipStream_t stream)
{
    const float* feat_A       = (const float*)d_in[0];
    const float* feat_B       = (const float*)d_in[1];
    const float* pe           = (const float*)d_in[2];
    const float* qkv_w_A      = (const float*)d_in[3];
    const float* qkv_b_A      = (const float*)d_in[4];
    const float* out_w_A      = (const float*)d_in[5];
    const float* out_b_A      = (const float*)d_in[6];
    const float* norm_g_A     = (const float*)d_in[7];
    const float* norm_b_A     = (const float*)d_in[8];
    const float* ffn_norm_g_A = (const float*)d_in[9];
    const float* ffn_norm_b_A = (const float*)d_in[10];
    const float* ffn_w1_A     = (const float*)d_in[11];
    const float* ffn_b1_A     = (const float*)d_in[12];
    const float* ffn_w2_A     = (const float*)d_in[13];
    const float* ffn_b2_A     = (const float*)d_in[14];
    const float* qkv_w_B      = (const float*)d_in[15];
    const float* qkv_b_B      = (const float*)d_in[16];
    const float* out_w_B      = (const float*)d_in[17];
    const float* out_b_B      = (const float*)d_in[18];
    const float* norm_g_B     = (const float*)d_in[19];
    const float* norm_b_B     = (const float*)d_in[20];
    const float* ffn_norm_g_B = (const float*)d_in[21];
    const float* ffn_norm_b_B = (const float*)d_in[22];
    const float* ffn_w1_B     = (const float*)d_in[23];
    const float* ffn_b1_B     = (const float*)d_in[24];
    const float* ffn_w2_B     = (const float*)d_in[25];
    const float* ffn_b2_B     = (const float*)d_in[26];

    char* ws = (char*)d_ws;
    const size_t BFE = (size_t)NTOK * 256;      // 16,777,216 elems
    const size_t BFB = BFE * 2;                 // 33.55 MB per bf16 buffer

    // round-5 proven buffer plan (270.4 MB); aw regions now pure scratch
    bf16* Wb = (bf16*)ws;                       // 1M bf16 = 2 MB
    size_t off = 2u * 1024 * 1024;
    bf16* awA = (bf16*)(ws + off); off += BFB;  // scratch (prep fused away)
    bf16* awB = (bf16*)(ws + off); off += BFB;
    bf16* qA  = (bf16*)(ws + off); off += BFB;
    bf16* kA  = (bf16*)(ws + off); off += BFB;
    bf16* vA  = (bf16*)(ws + off); off += BFB;
    bf16* qB  = (bf16*)(ws + off); off += BFB;
    bf16* kB  = (bf16*)(ws + off); off += BFB;
    bf16* vB  = (bf16*)(ws + off); off += BFB;
    bf16* tb1A = kA;   // out-proj scratch (kA dead after attn)
    bf16* tb1B = vA;   // (vA dead after attn)
    bf16* y1A = kB;    // LN1 out (kB dead after attn)
    bf16* y1B = vB;    // (vB dead after attn)
    bf16* hbA = awA;   // FFN hidden, spans awA+awB
    bf16* hbB = kA;    // spans kA+vA (tb1 consumed by ln1 before gelu)
    bf16* tb2A = qA;   // FFN2 scratch (qA dead after out-proj)
    bf16* tb2B = qB;

    bf16* w_qkvA = Wb + 0;
    bf16* w_outA = Wb + 196608;
    bf16* w_f1A  = Wb + 262144;
    bf16* w_f2A  = Wb + 393216;
    bf16* w_qkvB = Wb + 524288;
    bf16* w_outB = Wb + 720896;
    bf16* w_f1B  = Wb + 786432;
    bf16* w_f2B  = Wb + 917504;

    cvt8<<<1024, 256, 0, stream>>>(qkv_w_A, out_w_A, ffn_w1_A, ffn_w2_A,
                                   qkv_w_B, out_w_B, ffn_w1_B, ffn_w2_B, Wb);

    // QKV with fused window-partition + PE (prep_win eliminated)
    gemm_qkvf<<<6144, 256, 0, stream>>>(feat_A, feat_B, pe, w_qkvA, w_qkvB,
                                        qkv_b_A, qkv_b_B,
                                        qA, kA, vA, qB, kB, vB);

    attn_win2<<<2048, 256, 0, stream>>>(qA, kA, vA, qB, kB, vB);

    // out-proj both streams (unwin epilogue) -> tb1
    gemm_out<256, 1><<<2048, 256, 0, stream>>>(qA, qB, w_outA, w_outB,
                                               out_b_A, out_b_B, tb1A, tb1B);
    // LN1: y1 = LN(tb1 + feat) (bf16 out)
    ln_fz<1, 0><<<32768, 256, 0, stream>>>(tb1A, tb1B, feat_A, feat_B,
                                           nullptr, nullptr,
                                           norm_g_A, norm_g_B, norm_b_A, norm_b_B,
                                           nullptr, nullptr, y1A, y1B);
    // FFN1 both streams
    gemm_gelu<<<4096, 256, 0, stream>>>(y1A, y1B, w_f1A, w_f1B,
                                        ffn_b1_A, ffn_b1_B, hbA, hbB);
    // FFN2 both streams (linear epilogue) -> tb2
    gemm_out<512, 0><<<2048, 256, 0, stream>>>(hbA, hbB, w_f2A, w_f2B,
                                               ffn_b2_A, ffn_b2_B, tb2A, tb2B);
    // LN2: d_out = LN(tb2 + y1) (fp32 out)
    ln_fz<0, 1><<<32768, 256, 0, stream>>>(tb2A, tb2B, nullptr, nullptr,
                                           y1A, y1B,
                                           ffn_norm_g_A, ffn_norm_g_B,
                                           ffn_norm_b_A, ffn_norm_b_B,
                                           (float*)d_out, (float*)d_out + BFE,
                                           nullptr, nullptr);
}

// Round 13
// 481.909 us; speedup vs baseline: 1.0244x; 1.0244x over previous
//
#include <hip/hip_runtime.h>
#include <hip/hip_bf16.h>
#include <math.h>

typedef __bf16 bf16;
typedef __bf16 bf16x8 __attribute__((ext_vector_type(8)));
typedef __bf16 bf16x4 __attribute__((ext_vector_type(4)));
typedef float f32x4 __attribute__((ext_vector_type(4)));

#define NTOK 65536
#define DMODEL 256

// async global->LDS, 16B per lane; LDS dest = wave-uniform base + lane*16
#define GL16(g, l) __builtin_amdgcn_global_load_lds( \
    (const __attribute__((address_space(1))) void*)(g), \
    (__attribute__((address_space(3))) void*)(l), 16, 0, 0)

// window-order token m -> global token g (the _reverse mapping)
__device__ __forceinline__ int unwin_idx(int m) {
    int widx = m >> 6, t = m & 63;
    int b = widx >> 6, wl = widx & 63;
    return (b << 12) | (((wl >> 3) * 8 + (t >> 3)) << 6) | ((wl & 7) * 8 + (t & 7));
}

__device__ __forceinline__ float gelu_fast(float x) {
    float z = 0.7978845608f * (x + 0.044715f * x * x * x);
    float e = __expf(2.f * z);
    float t = (e - 1.f) / (e + 1.f);
    return 0.5f * x * (1.f + t);
}

// ---------------------------------------------------------------------------
// prep (round-5 PASSING version, verbatim)
// ---------------------------------------------------------------------------
__global__ __launch_bounds__(256)
void prep_win(const float* __restrict__ fA, const float* __restrict__ fB,
              const float* __restrict__ pe,
              bf16* __restrict__ awA, bf16* __restrict__ awB)
{
    const float* f = blockIdx.y ? fB : fA;
    bf16* aw = blockIdx.y ? awB : awA;
    int m = blockIdx.x * 8 + (threadIdx.x >> 5);
    int c = (threadIdx.x & 31) * 8;
    int g = unwin_idx(m), t = m & 63;
    const float4* fs = reinterpret_cast<const float4*>(f + (size_t)g * 256 + c);
    const float4* ps = reinterpret_cast<const float4*>(pe + t * 256 + c);
    float4 a0 = fs[0], a1 = fs[1], p0 = ps[0], p1 = ps[1];
    bf16x8 o;
    o[0] = (bf16)(a0.x + p0.x); o[1] = (bf16)(a0.y + p0.y);
    o[2] = (bf16)(a0.z + p0.z); o[3] = (bf16)(a0.w + p0.w);
    o[4] = (bf16)(a1.x + p1.x); o[5] = (bf16)(a1.y + p1.y);
    o[6] = (bf16)(a1.z + p1.z); o[7] = (bf16)(a1.w + p1.w);
    *reinterpret_cast<bf16x8*>(aw + (size_t)m * 256 + c) = o;
}

// ---------------------------------------------------------------------------
// weight convert (round-5 verbatim)
// ---------------------------------------------------------------------------
__global__ __launch_bounds__(256)
void cvt8(const float* __restrict__ s0, const float* __restrict__ s1,
          const float* __restrict__ s2, const float* __restrict__ s3,
          const float* __restrict__ s4, const float* __restrict__ s5,
          const float* __restrict__ s6, const float* __restrict__ s7,
          bf16* __restrict__ d)
{
    int idx = (blockIdx.x * 256 + threadIdx.x) * 4;
    const float* s; int off;
    if      (idx < 196608) { s = s0; off = 0; }
    else if (idx < 262144) { s = s1; off = 196608; }
    else if (idx < 393216) { s = s2; off = 262144; }
    else if (idx < 524288) { s = s3; off = 393216; }
    else if (idx < 720896) { s = s4; off = 524288; }
    else if (idx < 786432) { s = s5; off = 720896; }
    else if (idx < 917504) { s = s6; off = 786432; }
    else                   { s = s7; off = 917504; }
    float4 v = *reinterpret_cast<const float4*>(s + (idx - off));
    bf16x4 o; o[0] = (bf16)v.x; o[1] = (bf16)v.y; o[2] = (bf16)v.z; o[3] = (bf16)v.w;
    *reinterpret_cast<bf16x4*>(d + idx) = o;
}

// ---------------------------------------------------------------------------
// Merged QKV GEMM, both passes (round-5/11 PASSING version, verbatim).
// ---------------------------------------------------------------------------
__global__ __launch_bounds__(256, 4)
void gemm_qkv2(const bf16* __restrict__ awA, const bf16* __restrict__ awB,
               const bf16* __restrict__ wA, const bf16* __restrict__ wB,
               const float* __restrict__ bA, const float* __restrict__ bB,
               bf16* __restrict__ qA, bf16* __restrict__ kA, bf16* __restrict__ vA,
               bf16* __restrict__ qB, bf16* __restrict__ kB, bf16* __restrict__ vB)
{
    __shared__ bf16 As[2][4096];
    __shared__ bf16 Bs[2][4096];
    const int tid = threadIdx.x;
    const int bx = blockIdx.x;
    const int xcd = bx & 7, slot = bx >> 3;
    const int L = xcd * 768 + slot;
    const int mt = L / 6, nb = L - mt * 6;
    const int pass = mt >> 9, mb = mt & 511;
    const int seg = nb >> 1, nl0 = (nb & 1) * 128;
    const int m0 = mb * 128;

    const bf16* A = pass ? awB : awA;
    const bf16* Wf = (seg == 0) ? (pass ? wB : wA) : (pass ? wA : wB);
    const float* Bf = (seg == 0) ? (pass ? bB : bA) : (pass ? bA : bB);
    const bf16* W = Wf + (size_t)seg * 65536;
    const float* bia = Bf + seg * 256;
    bf16* qout = pass ? qB : qA;
    bf16* kout = pass ? kA : kB;
    bf16* vout = pass ? vA : vB;

    const int lane = tid & 63, w = tid >> 6;
    const int wr = w >> 1, wc = w & 1;
    const int lr = lane & 15, lg = lane >> 4;
    const int srow = tid >> 2, scol = (tid & 3) * 8;

    const bf16* Ag = A + (size_t)(m0 + srow) * 256 + scol;
    const bf16* Bg = W + (size_t)(nl0 + srow) * 256 + scol;

    f32x4 acc[4][4];
    const f32x4 zero = {0.f, 0.f, 0.f, 0.f};
#pragma unroll
    for (int mi = 0; mi < 4; ++mi)
#pragma unroll
        for (int nj = 0; nj < 4; ++nj) acc[mi][nj] = zero;

    auto stage = [&](int buf, int k0) {
        GL16(Ag + k0, &As[buf][tid * 8]);
        GL16(Ag + 64 * 256 + k0, &As[buf][2048 + tid * 8]);
        GL16(Bg + k0, &Bs[buf][tid * 8]);
        GL16(Bg + 64 * 256 + k0, &Bs[buf][2048 + tid * 8]);
    };
    auto compute = [&](int buf) {
        bf16x8 af[4], bfr[4];
#pragma unroll
        for (int mi = 0; mi < 4; ++mi)
            af[mi] = *reinterpret_cast<const bf16x8*>(&As[buf][(wr * 64 + mi * 16 + lr) * 32 + lg * 8]);
#pragma unroll
        for (int nj = 0; nj < 4; ++nj)
            bfr[nj] = *reinterpret_cast<const bf16x8*>(&Bs[buf][(wc * 64 + nj * 16 + lr) * 32 + lg * 8]);
#pragma unroll
        for (int mi = 0; mi < 4; ++mi)
#pragma unroll
            for (int nj = 0; nj < 4; ++nj)
                acc[mi][nj] = __builtin_amdgcn_mfma_f32_16x16x32_bf16(af[mi], bfr[nj], acc[mi][nj], 0, 0, 0);
    };

    stage(0, 0);
    __syncthreads();
#pragma unroll
    for (int t = 0; t < 7; ++t) {
        stage((t + 1) & 1, (t + 1) * 32);
        compute(t & 1);
        __syncthreads();
    }
    compute(1);

    if (seg == 2) {
        const int widx = mb * 2 + wr;
#pragma unroll
        for (int nj = 0; nj < 4; ++nj) {
            int cl = nl0 + wc * 64 + nj * 16 + lr;
            float bv = bia[cl];
#pragma unroll
            for (int mi = 0; mi < 4; ++mi) {
                bf16x4 o;
#pragma unroll
                for (int i = 0; i < 4; ++i) o[i] = (bf16)(acc[mi][nj][i] + bv);
                *reinterpret_cast<bf16x4*>(vout + ((size_t)widx * 256 + cl) * 64 + mi * 16 + lg * 4) = o;
            }
        }
    } else {
        bf16* out = (seg == 0) ? qout : kout;
#pragma unroll
        for (int nj = 0; nj < 4; ++nj) {
            int cl = nl0 + wc * 64 + nj * 16 + lr;
            float bv = bia[cl];
#pragma unroll
            for (int mi = 0; mi < 4; ++mi)
#pragma unroll
                for (int i = 0; i < 4; ++i) {
                    int row = m0 + wr * 64 + mi * 16 + lg * 4 + i;
                    out[(size_t)row * 256 + cl] = (bf16)(acc[mi][nj][i] + bv);
                }
        }
    }
}

// ---------------------------------------------------------------------------
// NEW: fused FFN (FFN1 + gelu + FFN2) per 128-row block — hb round-trip gone.
// Per nb (4 hidden slices of 128):
//   GEMM1: acc1 = y1[128 rows] @ w1[nb-slice]^T  (GL16 2-phase, proven)
//   gelu+bias -> Hs[128][136] (padded LDS, proven transpose-stage pattern)
//   GEMM2: acc2 += Hs @ w2[:, nb-slice]^T        (GL16 2-phase, A from Hs)
// Epilogue: acc2+b2 -> Hs -> coalesced bf16x8 stores (two 128-col passes).
// 512 threads (8 waves, 2x4). LDS: staging 32KB (phases share) + Hs 34.8KB.
// grid 1024 = 8 XCD chunks of 128; L -> str, mb.
// ---------------------------------------------------------------------------
__global__ __launch_bounds__(512, 2)
void gemm_ffn(const bf16* __restrict__ y1A, const bf16* __restrict__ y1B,
              const bf16* __restrict__ w1A, const bf16* __restrict__ w1B,
              const bf16* __restrict__ w2A, const bf16* __restrict__ w2B,
              const float* __restrict__ b1A, const float* __restrict__ b1B,
              const float* __restrict__ b2A, const float* __restrict__ b2B,
              bf16* __restrict__ tb2A, bf16* __restrict__ tb2B)
{
    __shared__ bf16 lds[33792];          // [0,16384): staging ; [16384,33792): Hs[128][136]
    bf16* Hs = lds + 16384;
    const int tid = threadIdx.x;
    const int bx = blockIdx.x;
    const int L = (bx & 7) * 128 + (bx >> 3);
    const int str = L >> 9, mb = L & 511;
    const int m0 = mb * 128;

    const bf16* Y  = str ? y1B : y1A;
    const bf16* W1 = str ? w1B : w1A;
    const bf16* W2 = str ? w2B : w2A;
    const float* b1 = str ? b1B : b1A;
    const float* b2 = str ? b2B : b2A;
    bf16* out = str ? tb2B : tb2A;

    const int w = tid >> 6, lane = tid & 63;
    const int wr = w >> 2, wc = w & 3;          // 2 x 4 wave grid
    const int lr = lane & 15, lg = lane >> 4;
    const int srow = tid >> 2, scol = (tid & 3) * 8;

    const bf16* Yg  = Y + (size_t)(m0 + srow) * 256 + scol;
    const bf16* W2g = W2 + (size_t)srow * 512 + scol;

    f32x4 acc2[4][4];
    const f32x4 zero = {0.f, 0.f, 0.f, 0.f};
#pragma unroll
    for (int mi = 0; mi < 4; ++mi)
#pragma unroll
        for (int nj = 0; nj < 4; ++nj) acc2[mi][nj] = zero;

    for (int nb = 0; nb < 4; ++nb) {
        const bf16* W1g = W1 + (size_t)(nb * 128 + srow) * 256 + scol;
        f32x4 acc1[4][2];
#pragma unroll
        for (int mi = 0; mi < 4; ++mi)
#pragma unroll
            for (int nj = 0; nj < 2; ++nj) acc1[mi][nj] = zero;

        auto stage1 = [&](int buf, int k0) {
            GL16(Yg + k0,  &lds[buf * 4096 + tid * 8]);          // As: y1 128x32
            GL16(W1g + k0, &lds[8192 + buf * 4096 + tid * 8]);   // Bs1: w1 slice 128x32
        };
        auto compute1 = [&](int buf) {
            bf16x8 af[4], bfr[2];
#pragma unroll
            for (int mi = 0; mi < 4; ++mi)
                af[mi] = *reinterpret_cast<const bf16x8*>(&lds[buf * 4096 + (wr * 64 + mi * 16 + lr) * 32 + lg * 8]);
#pragma unroll
            for (int nj = 0; nj < 2; ++nj)
                bfr[nj] = *reinterpret_cast<const bf16x8*>(&lds[8192 + buf * 4096 + (wc * 32 + nj * 16 + lr) * 32 + lg * 8]);
#pragma unroll
            for (int mi = 0; mi < 4; ++mi)
#pragma unroll
                for (int nj = 0; nj < 2; ++nj)
                    acc1[mi][nj] = __builtin_amdgcn_mfma_f32_16x16x32_bf16(af[mi], bfr[nj], acc1[mi][nj], 0, 0, 0);
        };

        stage1(0, 0);
        __syncthreads();
#pragma unroll
        for (int t = 0; t < 7; ++t) {
            stage1((t + 1) & 1, (t + 1) * 32);
            compute1(t & 1);
            __syncthreads();
        }
        compute1(1);

        // gelu + bias -> Hs (bijective 128x128 cover; Hs separate region)
#pragma unroll
        for (int nj = 0; nj < 2; ++nj) {
            int col = wc * 32 + nj * 16 + lr;
            float bv = b1[nb * 128 + col];
#pragma unroll
            for (int mi = 0; mi < 4; ++mi)
#pragma unroll
                for (int i = 0; i < 4; ++i) {
                    int row = wr * 64 + mi * 16 + lg * 4 + i;
                    Hs[row * 136 + col] = (bf16)gelu_fast(acc1[mi][nj][i] + bv);
                }
        }
        __syncthreads();   // Hs complete; staging region free for GEMM2

        auto stage2 = [&](int buf, int k0) {
            GL16(W2g + nb * 128 + k0, &lds[buf * 8192 + tid * 8]);               // w2 rows 0..127
            GL16(W2g + 128 * 512 + nb * 128 + k0, &lds[buf * 8192 + 4096 + tid * 8]); // rows 128..255
        };
        auto compute2 = [&](int buf, int k0) {
            bf16x8 af[4], bfr[4];
#pragma unroll
            for (int mi = 0; mi < 4; ++mi)
                af[mi] = *reinterpret_cast<const bf16x8*>(&Hs[(wr * 64 + mi * 16 + lr) * 136 + k0 + lg * 8]);
#pragma unroll
            for (int nj = 0; nj < 4; ++nj)
                bfr[nj] = *reinterpret_cast<const bf16x8*>(&lds[buf * 8192 + (wc * 64 + nj * 16 + lr) * 32 + lg * 8]);
#pragma unroll
            for (int mi = 0; mi < 4; ++mi)
#pragma unroll
                for (int nj = 0; nj < 4; ++nj)
                    acc2[mi][nj] = __builtin_amdgcn_mfma_f32_16x16x32_bf16(af[mi], bfr[nj], acc2[mi][nj], 0, 0, 0);
        };

        stage2(0, 0);
        __syncthreads();
#pragma unroll
        for (int t = 0; t < 3; ++t) {
            stage2((t + 1) & 1, (t + 1) * 32);
            compute2(t & 1, t * 32);
            __syncthreads();
        }
        compute2(1, 96);
        __syncthreads();   // drain before next nb overwrites staging/Hs
    }

    // epilogue: two 128-col passes through Hs, coalesced bf16x8 stores
#pragma unroll
    for (int h = 0; h < 2; ++h) {
        if ((wc >> 1) == h) {
#pragma unroll
            for (int nj = 0; nj < 4; ++nj) {
                int colw = nj * 16 + lr;
                float bv = b2[wc * 64 + colw];
                int coll = (wc & 1) * 64 + colw;
#pragma unroll
                for (int mi = 0; mi < 4; ++mi)
#pragma unroll
                    for (int i = 0; i < 4; ++i) {
                        int row = wr * 64 + mi * 16 + lg * 4 + i;
                        Hs[row * 136 + coll] = (bf16)(acc2[mi][nj][i] + bv);
                    }
            }
        }
        __syncthreads();
#pragma unroll
        for (int j = 0; j < 4; ++j) {
            int rowl = j * 32 + (tid >> 4);
            int coll = (tid & 15) * 8;
            *reinterpret_cast<bf16x8*>(out + (size_t)(m0 + rowl) * 256 + h * 128 + coll) =
                *reinterpret_cast<const bf16x8*>(&Hs[rowl * 136 + coll]);
        }
        __syncthreads();
    }
}

// ---------------------------------------------------------------------------
// gemm_out (round-11 PASSING version, verbatim).
// ---------------------------------------------------------------------------
template<int WK, int UNWIN>
__global__ __launch_bounds__(256, 4)
void gemm_out(const bf16* __restrict__ A0, const bf16* __restrict__ A1,
              const bf16* __restrict__ W0, const bf16* __restrict__ W1,
              const float* __restrict__ b0, const float* __restrict__ b1,
              bf16* __restrict__ C0, bf16* __restrict__ C1)
{
    __shared__ bf16 lds[17408];
    bf16* As = lds;
    bf16* Bs = lds + 8192;
    const int tid = threadIdx.x;
    const int bx = blockIdx.x;
    const int xcd = bx & 7, slot = bx >> 3;
    const int L = xcd * 256 + slot;
    const int mt = L >> 1, nb = L & 1;
    const int str = mt >> 9, mb = mt & 511;
    const int m0 = mb * 128, n0 = nb * 128;

    const bf16* A = str ? A1 : A0;
    const bf16* W = str ? W1 : W0;
    const float* bia = str ? b1 : b0;
    bf16* C = str ? C1 : C0;

    const int lane = tid & 63, w = tid >> 6;
    const int wr = w >> 1, wc = w & 1;
    const int lr = lane & 15, lg = lane >> 4;
    const int srow = tid >> 2, scol = (tid & 3) * 8;

    const bf16* Ag = A + (size_t)(m0 + srow) * WK + scol;
    const bf16* Bg = W + (size_t)(n0 + srow) * WK + scol;

    f32x4 acc[4][4];
    const f32x4 zero = {0.f, 0.f, 0.f, 0.f};
#pragma unroll
    for (int mi = 0; mi < 4; ++mi)
#pragma unroll
        for (int nj = 0; nj < 4; ++nj) acc[mi][nj] = zero;

    auto stage = [&](int buf, int k0) {
        GL16(Ag + k0, &As[buf * 4096 + tid * 8]);
        GL16(Ag + (size_t)64 * WK + k0, &As[buf * 4096 + 2048 + tid * 8]);
        GL16(Bg + k0, &Bs[buf * 4096 + tid * 8]);
        GL16(Bg + (size_t)64 * WK + k0, &Bs[buf * 4096 + 2048 + tid * 8]);
    };
    auto compute = [&](int buf) {
        bf16x8 af[4], bfr[4];
#pragma unroll
        for (int mi = 0; mi < 4; ++mi)
            af[mi] = *reinterpret_cast<const bf16x8*>(&As[buf * 4096 + (wr * 64 + mi * 16 + lr) * 32 + lg * 8]);
#pragma unroll
        for (int nj = 0; nj < 4; ++nj)
            bfr[nj] = *reinterpret_cast<const bf16x8*>(&Bs[buf * 4096 + (wc * 64 + nj * 16 + lr) * 32 + lg * 8]);
#pragma unroll
        for (int mi = 0; mi < 4; ++mi)
#pragma unroll
            for (int nj = 0; nj < 4; ++nj)
                acc[mi][nj] = __builtin_amdgcn_mfma_f32_16x16x32_bf16(af[mi], bfr[nj], acc[mi][nj], 0, 0, 0);
    };

    const int NT = WK / 32;
    stage(0, 0);
    __syncthreads();
#pragma unroll
    for (int t = 0; t < NT - 1; ++t) {
        stage((t + 1) & 1, (t + 1) * 32);
        compute(t & 1);
        __syncthreads();
    }
    compute((NT - 1) & 1);

    __syncthreads();
#pragma unroll
    for (int nj = 0; nj < 4; ++nj) {
        int coll = wc * 64 + nj * 16 + lr;
        float bv = bia[n0 + coll];
#pragma unroll
        for (int mi = 0; mi < 4; ++mi)
#pragma unroll
            for (int i = 0; i < 4; ++i) {
                int rowl = wr * 64 + mi * 16 + lg * 4 + i;
                lds[rowl * 136 + coll] = (bf16)(acc[mi][nj][i] + bv);
            }
    }
    __syncthreads();
#pragma unroll
    for (int j = 0; j < 4; ++j) {
        int rowl = j * 32 + (tid >> 3);
        int gr = UNWIN ? unwin_idx(m0 + rowl) : (m0 + rowl);
#pragma unroll
        for (int h = 0; h < 2; ++h) {
            int coll = h * 64 + (tid & 7) * 8;
            *reinterpret_cast<bf16x8*>(C + (size_t)gr * 256 + n0 + coll) =
                *reinterpret_cast<const bf16x8*>(&lds[rowl * 136 + coll]);
        }
    }
}

// ---------------------------------------------------------------------------
// ln_fz (round-10 PASSING version, verbatim)
// ---------------------------------------------------------------------------
template<int RESF, int OUTF>
__global__ __launch_bounds__(256)
void ln_fz(const bf16* __restrict__ x0, const bf16* __restrict__ x1,
           const float* __restrict__ rf0, const float* __restrict__ rf1,
           const bf16* __restrict__ rb0, const bf16* __restrict__ rb1,
           const float* __restrict__ g0, const float* __restrict__ g1,
           const float* __restrict__ be0, const float* __restrict__ be1,
           float* __restrict__ of0, float* __restrict__ of1,
           bf16* __restrict__ ob0, bf16* __restrict__ ob1)
{
    const int bx = blockIdx.x;
    const int str = bx >> 14, b = bx & 16383;
    const bf16* x = str ? x1 : x0;
    const float* rf = str ? rf1 : rf0;
    const bf16* rb = str ? rb1 : rb0;
    const float* gamma = str ? g1 : g0;
    const float* beta = str ? be1 : be0;
    float* outf = str ? of1 : of0;
    bf16* outb = str ? ob1 : ob0;

    int row = b * 4 + (threadIdx.x >> 6);
    int lane = threadIdx.x & 63;
    size_t base = (size_t)row * 256 + lane * 4;
    bf16x4 xv = *reinterpret_cast<const bf16x4*>(x + base);
    float v[4];
    if (RESF) {
        float4 rv = *reinterpret_cast<const float4*>(rf + base);
        v[0] = rv.x + (float)xv[0];
        v[1] = rv.y + (float)xv[1];
        v[2] = rv.z + (float)xv[2];
        v[3] = rv.w + (float)xv[3];
    } else {
        bf16x4 rv = *reinterpret_cast<const bf16x4*>(rb + base);
        v[0] = (float)rv[0] + (float)xv[0];
        v[1] = (float)rv[1] + (float)xv[1];
        v[2] = (float)rv[2] + (float)xv[2];
        v[3] = (float)rv[3] + (float)xv[3];
    }
    float s = v[0] + v[1] + v[2] + v[3];
    float q = v[0] * v[0] + v[1] * v[1] + v[2] * v[2] + v[3] * v[3];
#pragma unroll
    for (int m = 1; m < 64; m <<= 1) {
        s += __shfl_xor(s, m);
        q += __shfl_xor(q, m);
    }
    float mean = s * (1.f / 256.f);
    float var = q * (1.f / 256.f) - mean * mean;
    float rstd = rsqrtf(var + 1e-5f);
    float4 gv = *reinterpret_cast<const float4*>(gamma + lane * 4);
    float4 bv = *reinterpret_cast<const float4*>(beta + lane * 4);
    float o[4];
    o[0] = (v[0] - mean) * rstd * gv.x + bv.x;
    o[1] = (v[1] - mean) * rstd * gv.y + bv.y;
    o[2] = (v[2] - mean) * rstd * gv.z + bv.z;
    o[3] = (v[3] - mean) * rstd * gv.w + bv.w;
    if (OUTF) {
        float4 ov; ov.x = o[0]; ov.y = o[1]; ov.z = o[2]; ov.w = o[3];
        *reinterpret_cast<float4*>(outf + base) = ov;
    } else {
        bf16x4 ob;
        ob[0] = (bf16)o[0]; ob[1] = (bf16)o[1]; ob[2] = (bf16)o[2]; ob[3] = (bf16)o[3];
        *reinterpret_cast<bf16x4*>(outb + base) = ob;
    }
}

// ---------------------------------------------------------------------------
// Merged attention (round-5 PASSING version, verbatim).
// ---------------------------------------------------------------------------
__global__ __launch_bounds__(256)
void attn_win2(const bf16* qA, const bf16* __restrict__ kA,
               const bf16* __restrict__ vA,
               const bf16* qB, const bf16* __restrict__ kB,
               const bf16* __restrict__ vB)
{
    __shared__ bf16 Ps[4][64][72];
    const int tid = threadIdx.x;
    const int wv = tid >> 6, lane = tid & 63;
    const int str = blockIdx.x >> 10, widx = blockIdx.x & 1023, head = wv;
    const int lr = lane & 15, lg = lane >> 4;
    const bf16* qbuf = str ? qB : qA;
    const bf16* kbuf = str ? kB : kA;
    const bf16* vtbuf = str ? vB : vA;
    bf16* obuf = const_cast<bf16*>(qbuf);
    const bf16* qb = qbuf + (size_t)widx * 64 * 256 + head * 64;
    const bf16* kb = kbuf + (size_t)widx * 64 * 256 + head * 64;
    const bf16* vb = vtbuf + (size_t)widx * 16384 + head * 64 * 64;

    const f32x4 zero = {0.f, 0.f, 0.f, 0.f};
    f32x4 sacc[4][4];
#pragma unroll
    for (int mi = 0; mi < 4; ++mi)
#pragma unroll
        for (int nj = 0; nj < 4; ++nj) sacc[mi][nj] = zero;

#pragma unroll
    for (int k0 = 0; k0 < 64; k0 += 32) {
        bf16x8 af[4], bfr[4];
#pragma unroll
        for (int mi = 0; mi < 4; ++mi)
            af[mi] = *reinterpret_cast<const bf16x8*>(qb + (size_t)(mi * 16 + lr) * 256 + k0 + lg * 8);
#pragma unroll
        for (int nj = 0; nj < 4; ++nj)
            bfr[nj] = *reinterpret_cast<const bf16x8*>(kb + (size_t)(nj * 16 + lr) * 256 + k0 + lg * 8);
#pragma unroll
        for (int mi = 0; mi < 4; ++mi)
#pragma unroll
            for (int nj = 0; nj < 4; ++nj)
                sacc[mi][nj] = __builtin_amdgcn_mfma_f32_16x16x32_bf16(af[mi], bfr[nj], sacc[mi][nj], 0, 0, 0);
    }

    const float c = 0.125f * 1.4426950408889634f;  // log2(e)/sqrt(dh)
    float rsum[4][4];
#pragma unroll
    for (int mi = 0; mi < 4; ++mi)
#pragma unroll
        for (int i = 0; i < 4; ++i) {
            float m = fmaxf(fmaxf(sacc[mi][0][i], sacc[mi][1][i]), fmaxf(sacc[mi][2][i], sacc[mi][3][i]));
            m = fmaxf(m, __shfl_xor(m, 1));
            m = fmaxf(m, __shfl_xor(m, 2));
            m = fmaxf(m, __shfl_xor(m, 4));
            m = fmaxf(m, __shfl_xor(m, 8));
#pragma unroll
            for (int nj = 0; nj < 4; ++nj)
                sacc[mi][nj][i] = exp2f((sacc[mi][nj][i] - m) * c);
            float s = sacc[mi][0][i] + sacc[mi][1][i] + sacc[mi][2][i] + sacc[mi][3][i];
            s += __shfl_xor(s, 1);
            s += __shfl_xor(s, 2);
            s += __shfl_xor(s, 4);
            s += __shfl_xor(s, 8);
            rsum[mi][i] = s;
        }

#pragma unroll
    for (int mi = 0; mi < 4; ++mi)
#pragma unroll
        for (int nj = 0; nj < 4; ++nj)
#pragma unroll
            for (int i = 0; i < 4; ++i)
                Ps[wv][mi * 16 + lg * 4 + i][nj * 16 + lr] = (bf16)sacc[mi][nj][i];

    f32x4 oacc[4][4];
#pragma unroll
    for (int mi = 0; mi < 4; ++mi)
#pragma unroll
        for (int nj = 0; nj < 4; ++nj) oacc[mi][nj] = zero;
#pragma unroll
    for (int k0 = 0; k0 < 64; k0 += 32) {
        bf16x8 af[4], bfr[4];
#pragma unroll
        for (int mi = 0; mi < 4; ++mi)
            af[mi] = *reinterpret_cast<const bf16x8*>(&Ps[wv][mi * 16 + lr][k0 + lg * 8]);
#pragma unroll
        for (int nj = 0; nj < 4; ++nj)
            bfr[nj] = *reinterpret_cast<const bf16x8*>(vb + (size_t)(nj * 16 + lr) * 64 + k0 + lg * 8);
#pragma unroll
        for (int mi = 0; mi < 4; ++mi)
#pragma unroll
            for (int nj = 0; nj < 4; ++nj)
                oacc[mi][nj] = __builtin_amdgcn_mfma_f32_16x16x32_bf16(af[mi], bfr[nj], oacc[mi][nj], 0, 0, 0);
    }
#pragma unroll
    for (int mi = 0; mi < 4; ++mi)
#pragma unroll
        for (int i = 0; i < 4; ++i) {
            float inv = 1.0f / rsum[mi][i];
            int row = mi * 16 + lg * 4 + i;
#pragma unroll
            for (int nj = 0; nj < 4; ++nj)
                obuf[((size_t)widx * 64 + row) * 256 + head * 64 + nj * 16 + lr] =
                    (bf16)(oacc[mi][nj][i] * inv);
        }
}

extern "C" void kernel_launch(void* const* d_in, const int* in_sizes, int n_in,
                              void* d_out, int out_size, void* d_ws, size_t ws_size,
                              hipStream_t stream)
{
    const float* feat_A       = (const float*)d_in[0];
    const float* feat_B       = (const float*)d_in[1];
    const float* pe           = (const float*)d_in[2];
    const float* qkv_w_A      = (const float*)d_in[3];
    const float* qkv_b_A      = (const float*)d_in[4];
    const float* out_w_A      = (const float*)d_in[5];
    const float* out_b_A      = (const float*)d_in[6];
    const float* norm_g_A     = (const float*)d_in[7];
    const float* norm_b_A     = (const float*)d_in[8];
    const float* ffn_norm_g_A = (const float*)d_in[9];
    const float* ffn_norm_b_A = (const float*)d_in[10];
    const float* ffn_w1_A     = (const float*)d_in[11];
    const float* ffn_b1_A     = (const float*)d_in[12];
    const float* ffn_w2_A     = (const float*)d_in[13];
    const float* ffn_b2_A     = (const float*)d_in[14];
    const float* qkv_w_B      = (const float*)d_in[15];
    const float* qkv_b_B      = (const float*)d_in[16];
    const float* out_w_B      = (const float*)d_in[17];
    const float* out_b_B      = (const float*)d_in[18];
    const float* norm_g_B     = (const float*)d_in[19];
    const float* norm_b_B     = (const float*)d_in[20];
    const float* ffn_norm_g_B = (const float*)d_in[21];
    const float* ffn_norm_b_B = (const float*)d_in[22];
    const float* ffn_w1_B     = (const float*)d_in[23];
    const float* ffn_b1_B     = (const float*)d_in[24];
    const float* ffn_w2_B     = (const float*)d_in[25];
    const float* ffn_b2_B     = (const float*)d_in[26];

    char* ws = (char*)d_ws;
    const size_t BFE = (size_t)NTOK * 256;      // 16,777,216 elems
    const size_t BFB = BFE * 2;                 // 33.55 MB per bf16 buffer

    // round-5 proven buffer plan (270.4 MB)
    bf16* Wb = (bf16*)ws;                       // 1M bf16 = 2 MB
    size_t off = 2u * 1024 * 1024;
    bf16* awA = (bf16*)(ws + off); off += BFB;
    bf16* awB = (bf16*)(ws + off); off += BFB;
    bf16* qA  = (bf16*)(ws + off); off += BFB;
    bf16* kA  = (bf16*)(ws + off); off += BFB;
    bf16* vA  = (bf16*)(ws + off); off += BFB;
    bf16* qB  = (bf16*)(ws + off); off += BFB;
    bf16* kB  = (bf16*)(ws + off); off += BFB;
    bf16* vB  = (bf16*)(ws + off); off += BFB;
    bf16* tb1A = kA;   // out-proj scratch (kA dead after attn)
    bf16* tb1B = vA;   // (vA dead after attn)
    bf16* y1A = kB;    // LN1 out (kB dead after attn)
    bf16* y1B = vB;    // (vB dead after attn)
    bf16* tb2A = qA;   // FFN out scratch (qA dead after out-proj)
    bf16* tb2B = qB;

    bf16* w_qkvA = Wb + 0;
    bf16* w_outA = Wb + 196608;
    bf16* w_f1A  = Wb + 262144;
    bf16* w_f2A  = Wb + 393216;
    bf16* w_qkvB = Wb + 524288;
    bf16* w_outB = Wb + 720896;
    bf16* w_f1B  = Wb + 786432;
    bf16* w_f2B  = Wb + 917504;

    cvt8<<<1024, 256, 0, stream>>>(qkv_w_A, out_w_A, ffn_w1_A, ffn_w2_A,
                                   qkv_w_B, out_w_B, ffn_w1_B, ffn_w2_B, Wb);
    prep_win<<<dim3(8192, 2), 256, 0, stream>>>(feat_A, feat_B, pe, awA, awB);

    gemm_qkv2<<<6144, 256, 0, stream>>>(awA, awB, w_qkvA, w_qkvB,
                                        qkv_b_A, qkv_b_B,
                                        qA, kA, vA, qB, kB, vB);

    attn_win2<<<2048, 256, 0, stream>>>(qA, kA, vA, qB, kB, vB);

    // out-proj both streams (unwin epilogue) -> tb1
    gemm_out<256, 1><<<2048, 256, 0, stream>>>(qA, qB, w_outA, w_outB,
                                               out_b_A, out_b_B, tb1A, tb1B);
    // LN1: y1 = LN(tb1 + feat) (bf16 out)
    ln_fz<1, 0><<<32768, 256, 0, stream>>>(tb1A, tb1B, feat_A, feat_B,
                                           nullptr, nullptr,
                                           norm_g_A, norm_g_B, norm_b_A, norm_b_B,
                                           nullptr, nullptr, y1A, y1B);
    // fused FFN1+gelu+FFN2 -> tb2 (hb round-trip eliminated)
    gemm_ffn<<<1024, 512, 0, stream>>>(y1A, y1B, w_f1A, w_f1B, w_f2A, w_f2B,
                                       ffn_b1_A, ffn_b1_B, ffn_b2_A, ffn_b2_B,
                                       tb2A, tb2B);
    // LN2: d_out = LN(tb2 + y1) (fp32 out)
    ln_fz<0, 1><<<32768, 256, 0, stream>>>(tb2A, tb2B, nullptr, nullptr,
                                           y1A, y1B,
                                           ffn_norm_g_A, ffn_norm_g_B,
                                           ffn_norm_b_A, ffn_norm_b_B,
                                           (float*)d_out, (float*)d_out + BFE,
                                           nullptr, nullptr);
}

// Round 14
// 455.366 us; speedup vs baseline: 1.0842x; 1.0583x over previous
//
#include <hip/hip_runtime.h>
#include <hip/hip_bf16.h>
#include <math.h>

typedef __bf16 bf16;
typedef __bf16 bf16x8 __attribute__((ext_vector_type(8)));
typedef __bf16 bf16x4 __attribute__((ext_vector_type(4)));
typedef float f32x4 __attribute__((ext_vector_type(4)));

#define NTOK 65536
#define DMODEL 256

// async global->LDS, 16B per lane; LDS dest = wave-uniform base + lane*16
#define GL16(g, l) __builtin_amdgcn_global_load_lds( \
    (const __attribute__((address_space(1))) void*)(g), \
    (__attribute__((address_space(3))) void*)(l), 16, 0, 0)

// window-order token m -> global token g (the _reverse mapping)
__device__ __forceinline__ int unwin_idx(int m) {
    int widx = m >> 6, t = m & 63;
    int b = widx >> 6, wl = widx & 63;
    return (b << 12) | (((wl >> 3) * 8 + (t >> 3)) << 6) | ((wl & 7) * 8 + (t & 7));
}

__device__ __forceinline__ float gelu_fast(float x) {
    float z = 0.7978845608f * (x + 0.044715f * x * x * x);
    float e = __expf(2.f * z);
    float t = (e - 1.f) / (e + 1.f);
    return 0.5f * x * (1.f + t);
}

// ---------------------------------------------------------------------------
// prep (round-5 PASSING version, verbatim)
// ---------------------------------------------------------------------------
__global__ __launch_bounds__(256)
void prep_win(const float* __restrict__ fA, const float* __restrict__ fB,
              const float* __restrict__ pe,
              bf16* __restrict__ awA, bf16* __restrict__ awB)
{
    const float* f = blockIdx.y ? fB : fA;
    bf16* aw = blockIdx.y ? awB : awA;
    int m = blockIdx.x * 8 + (threadIdx.x >> 5);
    int c = (threadIdx.x & 31) * 8;
    int g = unwin_idx(m), t = m & 63;
    const float4* fs = reinterpret_cast<const float4*>(f + (size_t)g * 256 + c);
    const float4* ps = reinterpret_cast<const float4*>(pe + t * 256 + c);
    float4 a0 = fs[0], a1 = fs[1], p0 = ps[0], p1 = ps[1];
    bf16x8 o;
    o[0] = (bf16)(a0.x + p0.x); o[1] = (bf16)(a0.y + p0.y);
    o[2] = (bf16)(a0.z + p0.z); o[3] = (bf16)(a0.w + p0.w);
    o[4] = (bf16)(a1.x + p1.x); o[5] = (bf16)(a1.y + p1.y);
    o[6] = (bf16)(a1.z + p1.z); o[7] = (bf16)(a1.w + p1.w);
    *reinterpret_cast<bf16x8*>(aw + (size_t)m * 256 + c) = o;
}

// ---------------------------------------------------------------------------
// weight convert (round-5 verbatim)
// ---------------------------------------------------------------------------
__global__ __launch_bounds__(256)
void cvt8(const float* __restrict__ s0, const float* __restrict__ s1,
          const float* __restrict__ s2, const float* __restrict__ s3,
          const float* __restrict__ s4, const float* __restrict__ s5,
          const float* __restrict__ s6, const float* __restrict__ s7,
          bf16* __restrict__ d)
{
    int idx = (blockIdx.x * 256 + threadIdx.x) * 4;
    const float* s; int off;
    if      (idx < 196608) { s = s0; off = 0; }
    else if (idx < 262144) { s = s1; off = 196608; }
    else if (idx < 393216) { s = s2; off = 262144; }
    else if (idx < 524288) { s = s3; off = 393216; }
    else if (idx < 720896) { s = s4; off = 524288; }
    else if (idx < 786432) { s = s5; off = 720896; }
    else if (idx < 917504) { s = s6; off = 786432; }
    else                   { s = s7; off = 917504; }
    float4 v = *reinterpret_cast<const float4*>(s + (idx - off));
    bf16x4 o; o[0] = (bf16)v.x; o[1] = (bf16)v.y; o[2] = (bf16)v.z; o[3] = (bf16)v.w;
    *reinterpret_cast<bf16x4*>(d + idx) = o;
}

// ---------------------------------------------------------------------------
// Merged QKV GEMM, both passes (round-5/11 PASSING version, verbatim).
// ---------------------------------------------------------------------------
__global__ __launch_bounds__(256, 4)
void gemm_qkv2(const bf16* __restrict__ awA, const bf16* __restrict__ awB,
               const bf16* __restrict__ wA, const bf16* __restrict__ wB,
               const float* __restrict__ bA, const float* __restrict__ bB,
               bf16* __restrict__ qA, bf16* __restrict__ kA, bf16* __restrict__ vA,
               bf16* __restrict__ qB, bf16* __restrict__ kB, bf16* __restrict__ vB)
{
    __shared__ bf16 As[2][4096];
    __shared__ bf16 Bs[2][4096];
    const int tid = threadIdx.x;
    const int bx = blockIdx.x;
    const int xcd = bx & 7, slot = bx >> 3;
    const int L = xcd * 768 + slot;
    const int mt = L / 6, nb = L - mt * 6;
    const int pass = mt >> 9, mb = mt & 511;
    const int seg = nb >> 1, nl0 = (nb & 1) * 128;
    const int m0 = mb * 128;

    const bf16* A = pass ? awB : awA;
    const bf16* Wf = (seg == 0) ? (pass ? wB : wA) : (pass ? wA : wB);
    const float* Bf = (seg == 0) ? (pass ? bB : bA) : (pass ? bA : bB);
    const bf16* W = Wf + (size_t)seg * 65536;
    const float* bia = Bf + seg * 256;
    bf16* qout = pass ? qB : qA;
    bf16* kout = pass ? kA : kB;
    bf16* vout = pass ? vA : vB;

    const int lane = tid & 63, w = tid >> 6;
    const int wr = w >> 1, wc = w & 1;
    const int lr = lane & 15, lg = lane >> 4;
    const int srow = tid >> 2, scol = (tid & 3) * 8;

    const bf16* Ag = A + (size_t)(m0 + srow) * 256 + scol;
    const bf16* Bg = W + (size_t)(nl0 + srow) * 256 + scol;

    f32x4 acc[4][4];
    const f32x4 zero = {0.f, 0.f, 0.f, 0.f};
#pragma unroll
    for (int mi = 0; mi < 4; ++mi)
#pragma unroll
        for (int nj = 0; nj < 4; ++nj) acc[mi][nj] = zero;

    auto stage = [&](int buf, int k0) {
        GL16(Ag + k0, &As[buf][tid * 8]);
        GL16(Ag + 64 * 256 + k0, &As[buf][2048 + tid * 8]);
        GL16(Bg + k0, &Bs[buf][tid * 8]);
        GL16(Bg + 64 * 256 + k0, &Bs[buf][2048 + tid * 8]);
    };
    auto compute = [&](int buf) {
        bf16x8 af[4], bfr[4];
#pragma unroll
        for (int mi = 0; mi < 4; ++mi)
            af[mi] = *reinterpret_cast<const bf16x8*>(&As[buf][(wr * 64 + mi * 16 + lr) * 32 + lg * 8]);
#pragma unroll
        for (int nj = 0; nj < 4; ++nj)
            bfr[nj] = *reinterpret_cast<const bf16x8*>(&Bs[buf][(wc * 64 + nj * 16 + lr) * 32 + lg * 8]);
#pragma unroll
        for (int mi = 0; mi < 4; ++mi)
#pragma unroll
            for (int nj = 0; nj < 4; ++nj)
                acc[mi][nj] = __builtin_amdgcn_mfma_f32_16x16x32_bf16(af[mi], bfr[nj], acc[mi][nj], 0, 0, 0);
    };

    stage(0, 0);
    __syncthreads();
#pragma unroll
    for (int t = 0; t < 7; ++t) {
        stage((t + 1) & 1, (t + 1) * 32);
        compute(t & 1);
        __syncthreads();
    }
    compute(1);

    if (seg == 2) {
        const int widx = mb * 2 + wr;
#pragma unroll
        for (int nj = 0; nj < 4; ++nj) {
            int cl = nl0 + wc * 64 + nj * 16 + lr;
            float bv = bia[cl];
#pragma unroll
            for (int mi = 0; mi < 4; ++mi) {
                bf16x4 o;
#pragma unroll
                for (int i = 0; i < 4; ++i) o[i] = (bf16)(acc[mi][nj][i] + bv);
                *reinterpret_cast<bf16x4*>(vout + ((size_t)widx * 256 + cl) * 64 + mi * 16 + lg * 4) = o;
            }
        }
    } else {
        bf16* out = (seg == 0) ? qout : kout;
#pragma unroll
        for (int nj = 0; nj < 4; ++nj) {
            int cl = nl0 + wc * 64 + nj * 16 + lr;
            float bv = bia[cl];
#pragma unroll
            for (int mi = 0; mi < 4; ++mi)
#pragma unroll
                for (int i = 0; i < 4; ++i) {
                    int row = m0 + wr * 64 + mi * 16 + lg * 4 + i;
                    out[(size_t)row * 256 + cl] = (bf16)(acc[mi][nj][i] + bv);
                }
        }
    }
}

// ---------------------------------------------------------------------------
// Merged FFN1 (round-11 PASSING version, verbatim): gelu + coalesced epilogue.
// ---------------------------------------------------------------------------
__global__ __launch_bounds__(256, 4)
void gemm_gelu(const bf16* __restrict__ y1A, const bf16* __restrict__ y1B,
               const bf16* __restrict__ wA, const bf16* __restrict__ wB,
               const float* __restrict__ bA, const float* __restrict__ bB,
               bf16* __restrict__ hbA, bf16* __restrict__ hbB)
{
    __shared__ bf16 lds[17408];
    bf16* As = lds;
    bf16* Bs = lds + 8192;
    const int tid = threadIdx.x;
    const int bx = blockIdx.x;
    const int xcd = bx & 7, slot = bx >> 3;
    const int L = xcd * 512 + slot;
    const int mt = L >> 2, nb = L & 3;
    const int str = mt >> 9, mb = mt & 511;
    const int m0 = mb * 128, n0 = nb * 128;

    const bf16* A = str ? y1B : y1A;
    const bf16* W = str ? wB : wA;
    const float* bia = str ? bB : bA;
    bf16* C = str ? hbB : hbA;

    const int lane = tid & 63, w = tid >> 6;
    const int wr = w >> 1, wc = w & 1;
    const int lr = lane & 15, lg = lane >> 4;
    const int srow = tid >> 2, scol = (tid & 3) * 8;

    const bf16* Ag = A + (size_t)(m0 + srow) * 256 + scol;
    const bf16* Bg = W + (size_t)(n0 + srow) * 256 + scol;

    f32x4 acc[4][4];
    const f32x4 zero = {0.f, 0.f, 0.f, 0.f};
#pragma unroll
    for (int mi = 0; mi < 4; ++mi)
#pragma unroll
        for (int nj = 0; nj < 4; ++nj) acc[mi][nj] = zero;

    auto stage = [&](int buf, int k0) {
        GL16(Ag + k0, &As[buf * 4096 + tid * 8]);
        GL16(Ag + 64 * 256 + k0, &As[buf * 4096 + 2048 + tid * 8]);
        GL16(Bg + k0, &Bs[buf * 4096 + tid * 8]);
        GL16(Bg + 64 * 256 + k0, &Bs[buf * 4096 + 2048 + tid * 8]);
    };
    auto compute = [&](int buf) {
        bf16x8 af[4], bfr[4];
#pragma unroll
        for (int mi = 0; mi < 4; ++mi)
            af[mi] = *reinterpret_cast<const bf16x8*>(&As[buf * 4096 + (wr * 64 + mi * 16 + lr) * 32 + lg * 8]);
#pragma unroll
        for (int nj = 0; nj < 4; ++nj)
            bfr[nj] = *reinterpret_cast<const bf16x8*>(&Bs[buf * 4096 + (wc * 64 + nj * 16 + lr) * 32 + lg * 8]);
#pragma unroll
        for (int mi = 0; mi < 4; ++mi)
#pragma unroll
            for (int nj = 0; nj < 4; ++nj)
                acc[mi][nj] = __builtin_amdgcn_mfma_f32_16x16x32_bf16(af[mi], bfr[nj], acc[mi][nj], 0, 0, 0);
    };

    stage(0, 0);
    __syncthreads();
#pragma unroll
    for (int t = 0; t < 7; ++t) {
        stage((t + 1) & 1, (t + 1) * 32);
        compute(t & 1);
        __syncthreads();
    }
    compute(1);

    __syncthreads();
#pragma unroll
    for (int nj = 0; nj < 4; ++nj) {
        int coll = wc * 64 + nj * 16 + lr;
        float bv = bia[n0 + coll];
#pragma unroll
        for (int mi = 0; mi < 4; ++mi)
#pragma unroll
            for (int i = 0; i < 4; ++i) {
                int rowl = wr * 64 + mi * 16 + lg * 4 + i;
                lds[rowl * 136 + coll] = (bf16)gelu_fast(acc[mi][nj][i] + bv);
            }
    }
    __syncthreads();
#pragma unroll
    for (int j = 0; j < 4; ++j)
#pragma unroll
        for (int h = 0; h < 2; ++h) {
            int rowl = j * 32 + (tid >> 3);
            int coll = h * 64 + (tid & 7) * 8;
            *reinterpret_cast<bf16x8*>(C + (size_t)(m0 + rowl) * 512 + n0 + coll) =
                *reinterpret_cast<const bf16x8*>(&lds[rowl * 136 + coll]);
        }
}

// ---------------------------------------------------------------------------
// gemm_out (round-11 PASSING version, verbatim).
// ---------------------------------------------------------------------------
template<int WK, int UNWIN>
__global__ __launch_bounds__(256, 4)
void gemm_out(const bf16* __restrict__ A0, const bf16* __restrict__ A1,
              const bf16* __restrict__ W0, const bf16* __restrict__ W1,
              const float* __restrict__ b0, const float* __restrict__ b1,
              bf16* __restrict__ C0, bf16* __restrict__ C1)
{
    __shared__ bf16 lds[17408];
    bf16* As = lds;
    bf16* Bs = lds + 8192;
    const int tid = threadIdx.x;
    const int bx = blockIdx.x;
    const int xcd = bx & 7, slot = bx >> 3;
    const int L = xcd * 256 + slot;
    const int mt = L >> 1, nb = L & 1;
    const int str = mt >> 9, mb = mt & 511;
    const int m0 = mb * 128, n0 = nb * 128;

    const bf16* A = str ? A1 : A0;
    const bf16* W = str ? W1 : W0;
    const float* bia = str ? b1 : b0;
    bf16* C = str ? C1 : C0;

    const int lane = tid & 63, w = tid >> 6;
    const int wr = w >> 1, wc = w & 1;
    const int lr = lane & 15, lg = lane >> 4;
    const int srow = tid >> 2, scol = (tid & 3) * 8;

    const bf16* Ag = A + (size_t)(m0 + srow) * WK + scol;
    const bf16* Bg = W + (size_t)(n0 + srow) * WK + scol;

    f32x4 acc[4][4];
    const f32x4 zero = {0.f, 0.f, 0.f, 0.f};
#pragma unroll
    for (int mi = 0; mi < 4; ++mi)
#pragma unroll
        for (int nj = 0; nj < 4; ++nj) acc[mi][nj] = zero;

    auto stage = [&](int buf, int k0) {
        GL16(Ag + k0, &As[buf * 4096 + tid * 8]);
        GL16(Ag + (size_t)64 * WK + k0, &As[buf * 4096 + 2048 + tid * 8]);
        GL16(Bg + k0, &Bs[buf * 4096 + tid * 8]);
        GL16(Bg + (size_t)64 * WK + k0, &Bs[buf * 4096 + 2048 + tid * 8]);
    };
    auto compute = [&](int buf) {
        bf16x8 af[4], bfr[4];
#pragma unroll
        for (int mi = 0; mi < 4; ++mi)
            af[mi] = *reinterpret_cast<const bf16x8*>(&As[buf * 4096 + (wr * 64 + mi * 16 + lr) * 32 + lg * 8]);
#pragma unroll
        for (int nj = 0; nj < 4; ++nj)
            bfr[nj] = *reinterpret_cast<const bf16x8*>(&Bs[buf * 4096 + (wc * 64 + nj * 16 + lr) * 32 + lg * 8]);
#pragma unroll
        for (int mi = 0; mi < 4; ++mi)
#pragma unroll
            for (int nj = 0; nj < 4; ++nj)
                acc[mi][nj] = __builtin_amdgcn_mfma_f32_16x16x32_bf16(af[mi], bfr[nj], acc[mi][nj], 0, 0, 0);
    };

    const int NT = WK / 32;
    stage(0, 0);
    __syncthreads();
#pragma unroll
    for (int t = 0; t < NT - 1; ++t) {
        stage((t + 1) & 1, (t + 1) * 32);
        compute(t & 1);
        __syncthreads();
    }
    compute((NT - 1) & 1);

    __syncthreads();
#pragma unroll
    for (int nj = 0; nj < 4; ++nj) {
        int coll = wc * 64 + nj * 16 + lr;
        float bv = bia[n0 + coll];
#pragma unroll
        for (int mi = 0; mi < 4; ++mi)
#pragma unroll
            for (int i = 0; i < 4; ++i) {
                int rowl = wr * 64 + mi * 16 + lg * 4 + i;
                lds[rowl * 136 + coll] = (bf16)(acc[mi][nj][i] + bv);
            }
    }
    __syncthreads();
#pragma unroll
    for (int j = 0; j < 4; ++j) {
        int rowl = j * 32 + (tid >> 3);
        int gr = UNWIN ? unwin_idx(m0 + rowl) : (m0 + rowl);
#pragma unroll
        for (int h = 0; h < 2; ++h) {
            int coll = h * 64 + (tid & 7) * 8;
            *reinterpret_cast<bf16x8*>(C + (size_t)gr * 256 + n0 + coll) =
                *reinterpret_cast<const bf16x8*>(&lds[rowl * 136 + coll]);
        }
    }
}

// ---------------------------------------------------------------------------
// ln_fz (round-10 PASSING version, verbatim)
// ---------------------------------------------------------------------------
template<int RESF, int OUTF>
__global__ __launch_bounds__(256)
void ln_fz(const bf16* __restrict__ x0, const bf16* __restrict__ x1,
           const float* __restrict__ rf0, const float* __restrict__ rf1,
           const bf16* __restrict__ rb0, const bf16* __restrict__ rb1,
           const float* __restrict__ g0, const float* __restrict__ g1,
           const float* __restrict__ be0, const float* __restrict__ be1,
           float* __restrict__ of0, float* __restrict__ of1,
           bf16* __restrict__ ob0, bf16* __restrict__ ob1)
{
    const int bx = blockIdx.x;
    const int str = bx >> 14, b = bx & 16383;
    const bf16* x = str ? x1 : x0;
    const float* rf = str ? rf1 : rf0;
    const bf16* rb = str ? rb1 : rb0;
    const float* gamma = str ? g1 : g0;
    const float* beta = str ? be1 : be0;
    float* outf = str ? of1 : of0;
    bf16* outb = str ? ob1 : ob0;

    int row = b * 4 + (threadIdx.x >> 6);
    int lane = threadIdx.x & 63;
    size_t base = (size_t)row * 256 + lane * 4;
    bf16x4 xv = *reinterpret_cast<const bf16x4*>(x + base);
    float v[4];
    if (RESF) {
        float4 rv = *reinterpret_cast<const float4*>(rf + base);
        v[0] = rv.x + (float)xv[0];
        v[1] = rv.y + (float)xv[1];
        v[2] = rv.z + (float)xv[2];
        v[3] = rv.w + (float)xv[3];
    } else {
        bf16x4 rv = *reinterpret_cast<const bf16x4*>(rb + base);
        v[0] = (float)rv[0] + (float)xv[0];
        v[1] = (float)rv[1] + (float)xv[1];
        v[2] = (float)rv[2] + (float)xv[2];
        v[3] = (float)rv[3] + (float)xv[3];
    }
    float s = v[0] + v[1] + v[2] + v[3];
    float q = v[0] * v[0] + v[1] * v[1] + v[2] * v[2] + v[3] * v[3];
#pragma unroll
    for (int m = 1; m < 64; m <<= 1) {
        s += __shfl_xor(s, m);
        q += __shfl_xor(q, m);
    }
    float mean = s * (1.f / 256.f);
    float var = q * (1.f / 256.f) - mean * mean;
    float rstd = rsqrtf(var + 1e-5f);
    float4 gv = *reinterpret_cast<const float4*>(gamma + lane * 4);
    float4 bv = *reinterpret_cast<const float4*>(beta + lane * 4);
    float o[4];
    o[0] = (v[0] - mean) * rstd * gv.x + bv.x;
    o[1] = (v[1] - mean) * rstd * gv.y + bv.y;
    o[2] = (v[2] - mean) * rstd * gv.z + bv.z;
    o[3] = (v[3] - mean) * rstd * gv.w + bv.w;
    if (OUTF) {
        float4 ov; ov.x = o[0]; ov.y = o[1]; ov.z = o[2]; ov.w = o[3];
        *reinterpret_cast<float4*>(outf + base) = ov;
    } else {
        bf16x4 ob;
        ob[0] = (bf16)o[0]; ob[1] = (bf16)o[1]; ob[2] = (bf16)o[2]; ob[3] = (bf16)o[3];
        *reinterpret_cast<bf16x4*>(outb + base) = ob;
    }
}

// ---------------------------------------------------------------------------
// Merged attention (round-5 PASSING version, verbatim).
// ---------------------------------------------------------------------------
__global__ __launch_bounds__(256)
void attn_win2(const bf16* qA, const bf16* __restrict__ kA,
               const bf16* __restrict__ vA,
               const bf16* qB, const bf16* __restrict__ kB,
               const bf16* __restrict__ vB)
{
    __shared__ bf16 Ps[4][64][72];
    const int tid = threadIdx.x;
    const int wv = tid >> 6, lane = tid & 63;
    const int str = blockIdx.x >> 10, widx = blockIdx.x & 1023, head = wv;
    const int lr = lane & 15, lg = lane >> 4;
    const bf16* qbuf = str ? qB : qA;
    const bf16* kbuf = str ? kB : kA;
    const bf16* vtbuf = str ? vB : vA;
    bf16* obuf = const_cast<bf16*>(qbuf);
    const bf16* qb = qbuf + (size_t)widx * 64 * 256 + head * 64;
    const bf16* kb = kbuf + (size_t)widx * 64 * 256 + head * 64;
    const bf16* vb = vtbuf + (size_t)widx * 16384 + head * 64 * 64;

    const f32x4 zero = {0.f, 0.f, 0.f, 0.f};
    f32x4 sacc[4][4];
#pragma unroll
    for (int mi = 0; mi < 4; ++mi)
#pragma unroll
        for (int nj = 0; nj < 4; ++nj) sacc[mi][nj] = zero;

#pragma unroll
    for (int k0 = 0; k0 < 64; k0 += 32) {
        bf16x8 af[4], bfr[4];
#pragma unroll
        for (int mi = 0; mi < 4; ++mi)
            af[mi] = *reinterpret_cast<const bf16x8*>(qb + (size_t)(mi * 16 + lr) * 256 + k0 + lg * 8);
#pragma unroll
        for (int nj = 0; nj < 4; ++nj)
            bfr[nj] = *reinterpret_cast<const bf16x8*>(kb + (size_t)(nj * 16 + lr) * 256 + k0 + lg * 8);
#pragma unroll
        for (int mi = 0; mi < 4; ++mi)
#pragma unroll
            for (int nj = 0; nj < 4; ++nj)
                sacc[mi][nj] = __builtin_amdgcn_mfma_f32_16x16x32_bf16(af[mi], bfr[nj], sacc[mi][nj], 0, 0, 0);
    }

    const float c = 0.125f * 1.4426950408889634f;  // log2(e)/sqrt(dh)
    float rsum[4][4];
#pragma unroll
    for (int mi = 0; mi < 4; ++mi)
#pragma unroll
        for (int i = 0; i < 4; ++i) {
            float m = fmaxf(fmaxf(sacc[mi][0][i], sacc[mi][1][i]), fmaxf(sacc[mi][2][i], sacc[mi][3][i]));
            m = fmaxf(m, __shfl_xor(m, 1));
            m = fmaxf(m, __shfl_xor(m, 2));
            m = fmaxf(m, __shfl_xor(m, 4));
            m = fmaxf(m, __shfl_xor(m, 8));
#pragma unroll
            for (int nj = 0; nj < 4; ++nj)
                sacc[mi][nj][i] = exp2f((sacc[mi][nj][i] - m) * c);
            float s = sacc[mi][0][i] + sacc[mi][1][i] + sacc[mi][2][i] + sacc[mi][3][i];
            s += __shfl_xor(s, 1);
            s += __shfl_xor(s, 2);
            s += __shfl_xor(s, 4);
            s += __shfl_xor(s, 8);
            rsum[mi][i] = s;
        }

#pragma unroll
    for (int mi = 0; mi < 4; ++mi)
#pragma unroll
        for (int nj = 0; nj < 4; ++nj)
#pragma unroll
            for (int i = 0; i < 4; ++i)
                Ps[wv][mi * 16 + lg * 4 + i][nj * 16 + lr] = (bf16)sacc[mi][nj][i];

    f32x4 oacc[4][4];
#pragma unroll
    for (int mi = 0; mi < 4; ++mi)
#pragma unroll
        for (int nj = 0; nj < 4; ++nj) oacc[mi][nj] = zero;
#pragma unroll
    for (int k0 = 0; k0 < 64; k0 += 32) {
        bf16x8 af[4], bfr[4];
#pragma unroll
        for (int mi = 0; mi < 4; ++mi)
            af[mi] = *reinterpret_cast<const bf16x8*>(&Ps[wv][mi * 16 + lr][k0 + lg * 8]);
#pragma unroll
        for (int nj = 0; nj < 4; ++nj)
            bfr[nj] = *reinterpret_cast<const bf16x8*>(vb + (size_t)(nj * 16 + lr) * 64 + k0 + lg * 8);
#pragma unroll
        for (int mi = 0; mi < 4; ++mi)
#pragma unroll
            for (int nj = 0; nj < 4; ++nj)
                oacc[mi][nj] = __builtin_amdgcn_mfma_f32_16x16x32_bf16(af[mi], bfr[nj], oacc[mi][nj], 0, 0, 0);
    }
#pragma unroll
    for (int mi = 0; mi < 4; ++mi)
#pragma unroll
        for (int i = 0; i < 4; ++i) {
            float inv = 1.0f / rsum[mi][i];
            int row = mi * 16 + lg * 4 + i;
#pragma unroll
            for (int nj = 0; nj < 4; ++nj)
                obuf[((size_t)widx * 64 + row) * 256 + head * 64 + nj * 16 + lr] =
                    (bf16)(oacc[mi][nj][i] * inv);
        }
}

extern "C" void kernel_launch(void* const* d_in, const int* in_sizes, int n_in,
                              void* d_out, int out_size, void* d_ws, size_t ws_size,
                              hipStream_t stream)
{
    const float* feat_A       = (const float*)d_in[0];
    const float* feat_B       = (const float*)d_in[1];
    const float* pe           = (const float*)d_in[2];
    const float* qkv_w_A      = (const float*)d_in[3];
    const float* qkv_b_A      = (const float*)d_in[4];
    const float* out_w_A      = (const float*)d_in[5];
    const float* out_b_A      = (const float*)d_in[6];
    const float* norm_g_A     = (const float*)d_in[7];
    const float* norm_b_A     = (const float*)d_in[8];
    const float* ffn_norm_g_A = (const float*)d_in[9];
    const float* ffn_norm_b_A = (const float*)d_in[10];
    const float* ffn_w1_A     = (const float*)d_in[11];
    const float* ffn_b1_A     = (const float*)d_in[12];
    const float* ffn_w2_A     = (const float*)d_in[13];
    const float* ffn_b2_A     = (const float*)d_in[14];
    const float* qkv_w_B      = (const float*)d_in[15];
    const float* qkv_b_B      = (const float*)d_in[16];
    const float* out_w_B      = (const float*)d_in[17];
    const float* out_b_B      = (const float*)d_in[18];
    const float* norm_g_B     = (const float*)d_in[19];
    const float* norm_b_B     = (const float*)d_in[20];
    const float* ffn_norm_g_B = (const float*)d_in[21];
    const float* ffn_norm_b_B = (const float*)d_in[22];
    const float* ffn_w1_B     = (const float*)d_in[23];
    const float* ffn_b1_B     = (const float*)d_in[24];
    const float* ffn_w2_B     = (const float*)d_in[25];
    const float* ffn_b2_B     = (const float*)d_in[26];

    char* ws = (char*)d_ws;
    const size_t BFE = (size_t)NTOK * 256;      // 16,777,216 elems
    const size_t BFB = BFE * 2;                 // 33.55 MB per bf16 buffer

    // round-5 proven buffer plan (270.4 MB) + liveness reuse:
    bf16* Wb = (bf16*)ws;                       // 1M bf16 = 2 MB
    size_t off = 2u * 1024 * 1024;
    bf16* awA = (bf16*)(ws + off); off += BFB;
    bf16* awB = (bf16*)(ws + off); off += BFB;
    bf16* qA  = (bf16*)(ws + off); off += BFB;
    bf16* kA  = (bf16*)(ws + off); off += BFB;
    bf16* vA  = (bf16*)(ws + off); off += BFB;
    bf16* qB  = (bf16*)(ws + off); off += BFB;
    bf16* kB  = (bf16*)(ws + off); off += BFB;
    bf16* vB  = (bf16*)(ws + off); off += BFB;
    bf16* tb1A = kA;   // out-proj scratch (kA dead after attn)
    bf16* tb1B = vA;   // (vA dead after attn)
    bf16* y1A = kB;    // LN1 out (kB dead after attn)
    bf16* y1B = vB;    // (vB dead after attn)
    bf16* hbA = awA;   // FFN hidden, spans awA+awB
    bf16* hbB = kA;    // spans kA+vA (tb1 consumed by ln1 before gelu)
    bf16* tb2A = qA;   // FFN2 scratch (qA dead after out-proj)
    bf16* tb2B = qB;

    bf16* w_qkvA = Wb + 0;
    bf16* w_outA = Wb + 196608;
    bf16* w_f1A  = Wb + 262144;
    bf16* w_f2A  = Wb + 393216;
    bf16* w_qkvB = Wb + 524288;
    bf16* w_outB = Wb + 720896;
    bf16* w_f1B  = Wb + 786432;
    bf16* w_f2B  = Wb + 917504;

    cvt8<<<1024, 256, 0, stream>>>(qkv_w_A, out_w_A, ffn_w1_A, ffn_w2_A,
                                   qkv_w_B, out_w_B, ffn_w1_B, ffn_w2_B, Wb);
    prep_win<<<dim3(8192, 2), 256, 0, stream>>>(feat_A, feat_B, pe, awA, awB);

    gemm_qkv2<<<6144, 256, 0, stream>>>(awA, awB, w_qkvA, w_qkvB,
                                        qkv_b_A, qkv_b_B,
                                        qA, kA, vA, qB, kB, vB);

    attn_win2<<<2048, 256, 0, stream>>>(qA, kA, vA, qB, kB, vB);

    // out-proj both streams (unwin epilogue) -> tb1
    gemm_out<256, 1><<<2048, 256, 0, stream>>>(qA, qB, w_outA, w_outB,
                                               out_b_A, out_b_B, tb1A, tb1B);
    // LN1: y1 = LN(tb1 + feat) (bf16 out)
    ln_fz<1, 0><<<32768, 256, 0, stream>>>(tb1A, tb1B, feat_A, feat_B,
                                           nullptr, nullptr,
                                           norm_g_A, norm_g_B, norm_b_A, norm_b_B,
                                           nullptr, nullptr, y1A, y1B);
    // FFN1 both streams
    gemm_gelu<<<4096, 256, 0, stream>>>(y1A, y1B, w_f1A, w_f1B,
                                        ffn_b1_A, ffn_b1_B, hbA, hbB);
    // FFN2 both streams (linear epilogue) -> tb2
    gemm_out<512, 0><<<2048, 256, 0, stream>>>(hbA, hbB, w_f2A, w_f2B,
                                               ffn_b2_A, ffn_b2_B, tb2A, tb2B);
    // LN2: d_out = LN(tb2 + y1) (fp32 out)
    ln_fz<0, 1><<<32768, 256, 0, stream>>>(tb2A, tb2B, nullptr, nullptr,
                                           y1A, y1B,
                                           ffn_norm_g_A, ffn_norm_g_B,
                                           ffn_norm_b_A, ffn_norm_b_B,
                                           (float*)d_out, (float*)d_out + BFE,
                                           nullptr, nullptr);
}

// Round 15
// 454.402 us; speedup vs baseline: 1.0865x; 1.0021x over previous
//
#include <hip/hip_runtime.h>
#include <hip/hip_bf16.h>
#include <math.h>

typedef __bf16 bf16;
typedef __bf16 bf16x8 __attribute__((ext_vector_type(8)));
typedef __bf16 bf16x4 __attribute__((ext_vector_type(4)));
typedef float f32x4 __attribute__((ext_vector_type(4)));

#define NTOK 65536
#define DMODEL 256

// async global->LDS, 16B per lane; LDS dest = wave-uniform base + lane*16
#define GL16(g, l) __builtin_amdgcn_global_load_lds( \
    (const __attribute__((address_space(1))) void*)(g), \
    (__attribute__((address_space(3))) void*)(l), 16, 0, 0)

// counted waits for the 3-buffer pipeline (rule-18 guard: memory clobber +
// sched_barrier keeps ds_reads from hoisting above the wait)
#define WAITV(N) do { asm volatile("s_waitcnt vmcnt(" #N ")" ::: "memory"); \
                      __builtin_amdgcn_sched_barrier(0); } while (0)

// window-order token m -> global token g (the _reverse mapping)
__device__ __forceinline__ int unwin_idx(int m) {
    int widx = m >> 6, t = m & 63;
    int b = widx >> 6, wl = widx & 63;
    return (b << 12) | (((wl >> 3) * 8 + (t >> 3)) << 6) | ((wl & 7) * 8 + (t & 7));
}

__device__ __forceinline__ float gelu_fast(float x) {
    float z = 0.7978845608f * (x + 0.044715f * x * x * x);
    float e = __expf(2.f * z);
    float t = (e - 1.f) / (e + 1.f);
    return 0.5f * x * (1.f + t);
}

// ---------------------------------------------------------------------------
// prep (round-5 PASSING version, verbatim)
// ---------------------------------------------------------------------------
__global__ __launch_bounds__(256)
void prep_win(const float* __restrict__ fA, const float* __restrict__ fB,
              const float* __restrict__ pe,
              bf16* __restrict__ awA, bf16* __restrict__ awB)
{
    const float* f = blockIdx.y ? fB : fA;
    bf16* aw = blockIdx.y ? awB : awA;
    int m = blockIdx.x * 8 + (threadIdx.x >> 5);
    int c = (threadIdx.x & 31) * 8;
    int g = unwin_idx(m), t = m & 63;
    const float4* fs = reinterpret_cast<const float4*>(f + (size_t)g * 256 + c);
    const float4* ps = reinterpret_cast<const float4*>(pe + t * 256 + c);
    float4 a0 = fs[0], a1 = fs[1], p0 = ps[0], p1 = ps[1];
    bf16x8 o;
    o[0] = (bf16)(a0.x + p0.x); o[1] = (bf16)(a0.y + p0.y);
    o[2] = (bf16)(a0.z + p0.z); o[3] = (bf16)(a0.w + p0.w);
    o[4] = (bf16)(a1.x + p1.x); o[5] = (bf16)(a1.y + p1.y);
    o[6] = (bf16)(a1.z + p1.z); o[7] = (bf16)(a1.w + p1.w);
    *reinterpret_cast<bf16x8*>(aw + (size_t)m * 256 + c) = o;
}

// ---------------------------------------------------------------------------
// weight convert (round-5 verbatim)
// ---------------------------------------------------------------------------
__global__ __launch_bounds__(256)
void cvt8(const float* __restrict__ s0, const float* __restrict__ s1,
          const float* __restrict__ s2, const float* __restrict__ s3,
          const float* __restrict__ s4, const float* __restrict__ s5,
          const float* __restrict__ s6, const float* __restrict__ s7,
          bf16* __restrict__ d)
{
    int idx = (blockIdx.x * 256 + threadIdx.x) * 4;
    const float* s; int off;
    if      (idx < 196608) { s = s0; off = 0; }
    else if (idx < 262144) { s = s1; off = 196608; }
    else if (idx < 393216) { s = s2; off = 262144; }
    else if (idx < 524288) { s = s3; off = 393216; }
    else if (idx < 720896) { s = s4; off = 524288; }
    else if (idx < 786432) { s = s5; off = 720896; }
    else if (idx < 917504) { s = s6; off = 786432; }
    else                   { s = s7; off = 917504; }
    float4 v = *reinterpret_cast<const float4*>(s + (idx - off));
    bf16x4 o; o[0] = (bf16)v.x; o[1] = (bf16)v.y; o[2] = (bf16)v.z; o[3] = (bf16)v.w;
    *reinterpret_cast<bf16x4*>(d + idx) = o;
}

// ---------------------------------------------------------------------------
// Merged QKV GEMM, both passes — NEW: 3-buffer pipeline, counted vmcnt(4).
// Decode, staging addresses, compute, and epilogues byte-identical to the
// round-14 passing version; only the buffering/sync schedule changed.
// ---------------------------------------------------------------------------
__global__ __launch_bounds__(256, 3)
void gemm_qkv2(const bf16* __restrict__ awA, const bf16* __restrict__ awB,
               const bf16* __restrict__ wA, const bf16* __restrict__ wB,
               const float* __restrict__ bA, const float* __restrict__ bB,
               bf16* __restrict__ qA, bf16* __restrict__ kA, bf16* __restrict__ vA,
               bf16* __restrict__ qB, bf16* __restrict__ kB, bf16* __restrict__ vB)
{
    __shared__ bf16 As[3][4096];
    __shared__ bf16 Bs[3][4096];
    const int tid = threadIdx.x;
    const int bx = blockIdx.x;
    const int xcd = bx & 7, slot = bx >> 3;
    const int L = xcd * 768 + slot;
    const int mt = L / 6, nb = L - mt * 6;
    const int pass = mt >> 9, mb = mt & 511;
    const int seg = nb >> 1, nl0 = (nb & 1) * 128;
    const int m0 = mb * 128;

    const bf16* A = pass ? awB : awA;
    const bf16* Wf = (seg == 0) ? (pass ? wB : wA) : (pass ? wA : wB);
    const float* Bf = (seg == 0) ? (pass ? bB : bA) : (pass ? bA : bB);
    const bf16* W = Wf + (size_t)seg * 65536;
    const float* bia = Bf + seg * 256;
    bf16* qout = pass ? qB : qA;
    bf16* kout = pass ? kA : kB;
    bf16* vout = pass ? vA : vB;

    const int lane = tid & 63, w = tid >> 6;
    const int wr = w >> 1, wc = w & 1;
    const int lr = lane & 15, lg = lane >> 4;
    const int srow = tid >> 2, scol = (tid & 3) * 8;

    const bf16* Ag = A + (size_t)(m0 + srow) * 256 + scol;
    const bf16* Bg = W + (size_t)(nl0 + srow) * 256 + scol;

    f32x4 acc[4][4];
    const f32x4 zero = {0.f, 0.f, 0.f, 0.f};
#pragma unroll
    for (int mi = 0; mi < 4; ++mi)
#pragma unroll
        for (int nj = 0; nj < 4; ++nj) acc[mi][nj] = zero;

    auto stage = [&](int buf, int k0) {
        GL16(Ag + k0, &As[buf][tid * 8]);
        GL16(Ag + 64 * 256 + k0, &As[buf][2048 + tid * 8]);
        GL16(Bg + k0, &Bs[buf][tid * 8]);
        GL16(Bg + 64 * 256 + k0, &Bs[buf][2048 + tid * 8]);
    };
    auto compute = [&](int buf) {
        bf16x8 af[4], bfr[4];
#pragma unroll
        for (int mi = 0; mi < 4; ++mi)
            af[mi] = *reinterpret_cast<const bf16x8*>(&As[buf][(wr * 64 + mi * 16 + lr) * 32 + lg * 8]);
#pragma unroll
        for (int nj = 0; nj < 4; ++nj)
            bfr[nj] = *reinterpret_cast<const bf16x8*>(&Bs[buf][(wc * 64 + nj * 16 + lr) * 32 + lg * 8]);
#pragma unroll
        for (int mi = 0; mi < 4; ++mi)
#pragma unroll
            for (int nj = 0; nj < 4; ++nj)
                acc[mi][nj] = __builtin_amdgcn_mfma_f32_16x16x32_bf16(af[mi], bfr[nj], acc[mi][nj], 0, 0, 0);
    };

    // prologue: two stages in flight; wait only the oldest
    stage(0, 0);
    stage(1, 32);
    WAITV(4);                    // buf0 complete; buf1's 4 loads in flight
    __builtin_amdgcn_s_barrier();

#pragma unroll
    for (int t = 0; t < 7; ++t) {
        if (t < 6) stage((t + 2) % 3, (t + 2) * 32);   // 2-ahead prefetch
        compute(t % 3);
        if (t < 6) { WAITV(4); }                       // t+1 done; t+2 in flight
        else       { WAITV(0); }                       // drain for final step
        __builtin_amdgcn_s_barrier();
    }
    compute(7 % 3);   // buf1; loads guaranteed complete by the t=6 drain

    if (seg == 2) {
        const int widx = mb * 2 + wr;
#pragma unroll
        for (int nj = 0; nj < 4; ++nj) {
            int cl = nl0 + wc * 64 + nj * 16 + lr;
            float bv = bia[cl];
#pragma unroll
            for (int mi = 0; mi < 4; ++mi) {
                bf16x4 o;
#pragma unroll
                for (int i = 0; i < 4; ++i) o[i] = (bf16)(acc[mi][nj][i] + bv);
                *reinterpret_cast<bf16x4*>(vout + ((size_t)widx * 256 + cl) * 64 + mi * 16 + lg * 4) = o;
            }
        }
    } else {
        bf16* out = (seg == 0) ? qout : kout;
#pragma unroll
        for (int nj = 0; nj < 4; ++nj) {
            int cl = nl0 + wc * 64 + nj * 16 + lr;
            float bv = bia[cl];
#pragma unroll
            for (int mi = 0; mi < 4; ++mi)
#pragma unroll
                for (int i = 0; i < 4; ++i) {
                    int row = m0 + wr * 64 + mi * 16 + lg * 4 + i;
                    out[(size_t)row * 256 + cl] = (bf16)(acc[mi][nj][i] + bv);
                }
        }
    }
}

// ---------------------------------------------------------------------------
// Merged FFN1 (round-11 PASSING version, verbatim): gelu + coalesced epilogue.
// ---------------------------------------------------------------------------
__global__ __launch_bounds__(256, 4)
void gemm_gelu(const bf16* __restrict__ y1A, const bf16* __restrict__ y1B,
               const bf16* __restrict__ wA, const bf16* __restrict__ wB,
               const float* __restrict__ bA, const float* __restrict__ bB,
               bf16* __restrict__ hbA, bf16* __restrict__ hbB)
{
    __shared__ bf16 lds[17408];
    bf16* As = lds;
    bf16* Bs = lds + 8192;
    const int tid = threadIdx.x;
    const int bx = blockIdx.x;
    const int xcd = bx & 7, slot = bx >> 3;
    const int L = xcd * 512 + slot;
    const int mt = L >> 2, nb = L & 3;
    const int str = mt >> 9, mb = mt & 511;
    const int m0 = mb * 128, n0 = nb * 128;

    const bf16* A = str ? y1B : y1A;
    const bf16* W = str ? wB : wA;
    const float* bia = str ? bB : bA;
    bf16* C = str ? hbB : hbA;

    const int lane = tid & 63, w = tid >> 6;
    const int wr = w >> 1, wc = w & 1;
    const int lr = lane & 15, lg = lane >> 4;
    const int srow = tid >> 2, scol = (tid & 3) * 8;

    const bf16* Ag = A + (size_t)(m0 + srow) * 256 + scol;
    const bf16* Bg = W + (size_t)(n0 + srow) * 256 + scol;

    f32x4 acc[4][4];
    const f32x4 zero = {0.f, 0.f, 0.f, 0.f};
#pragma unroll
    for (int mi = 0; mi < 4; ++mi)
#pragma unroll
        for (int nj = 0; nj < 4; ++nj) acc[mi][nj] = zero;

    auto stage = [&](int buf, int k0) {
        GL16(Ag + k0, &As[buf * 4096 + tid * 8]);
        GL16(Ag + 64 * 256 + k0, &As[buf * 4096 + 2048 + tid * 8]);
        GL16(Bg + k0, &Bs[buf * 4096 + tid * 8]);
        GL16(Bg + 64 * 256 + k0, &Bs[buf * 4096 + 2048 + tid * 8]);
    };
    auto compute = [&](int buf) {
        bf16x8 af[4], bfr[4];
#pragma unroll
        for (int mi = 0; mi < 4; ++mi)
            af[mi] = *reinterpret_cast<const bf16x8*>(&As[buf * 4096 + (wr * 64 + mi * 16 + lr) * 32 + lg * 8]);
#pragma unroll
        for (int nj = 0; nj < 4; ++nj)
            bfr[nj] = *reinterpret_cast<const bf16x8*>(&Bs[buf * 4096 + (wc * 64 + nj * 16 + lr) * 32 + lg * 8]);
#pragma unroll
        for (int mi = 0; mi < 4; ++mi)
#pragma unroll
            for (int nj = 0; nj < 4; ++nj)
                acc[mi][nj] = __builtin_amdgcn_mfma_f32_16x16x32_bf16(af[mi], bfr[nj], acc[mi][nj], 0, 0, 0);
    };

    stage(0, 0);
    __syncthreads();
#pragma unroll
    for (int t = 0; t < 7; ++t) {
        stage((t + 1) & 1, (t + 1) * 32);
        compute(t & 1);
        __syncthreads();
    }
    compute(1);

    __syncthreads();
#pragma unroll
    for (int nj = 0; nj < 4; ++nj) {
        int coll = wc * 64 + nj * 16 + lr;
        float bv = bia[n0 + coll];
#pragma unroll
        for (int mi = 0; mi < 4; ++mi)
#pragma unroll
            for (int i = 0; i < 4; ++i) {
                int rowl = wr * 64 + mi * 16 + lg * 4 + i;
                lds[rowl * 136 + coll] = (bf16)gelu_fast(acc[mi][nj][i] + bv);
            }
    }
    __syncthreads();
#pragma unroll
    for (int j = 0; j < 4; ++j)
#pragma unroll
        for (int h = 0; h < 2; ++h) {
            int rowl = j * 32 + (tid >> 3);
            int coll = h * 64 + (tid & 7) * 8;
            *reinterpret_cast<bf16x8*>(C + (size_t)(m0 + rowl) * 512 + n0 + coll) =
                *reinterpret_cast<const bf16x8*>(&lds[rowl * 136 + coll]);
        }
}

// ---------------------------------------------------------------------------
// gemm_out (round-11 PASSING version, verbatim).
// ---------------------------------------------------------------------------
template<int WK, int UNWIN>
__global__ __launch_bounds__(256, 4)
void gemm_out(const bf16* __restrict__ A0, const bf16* __restrict__ A1,
              const bf16* __restrict__ W0, const bf16* __restrict__ W1,
              const float* __restrict__ b0, const float* __restrict__ b1,
              bf16* __restrict__ C0, bf16* __restrict__ C1)
{
    __shared__ bf16 lds[17408];
    bf16* As = lds;
    bf16* Bs = lds + 8192;
    const int tid = threadIdx.x;
    const int bx = blockIdx.x;
    const int xcd = bx & 7, slot = bx >> 3;
    const int L = xcd * 256 + slot;
    const int mt = L >> 1, nb = L & 1;
    const int str = mt >> 9, mb = mt & 511;
    const int m0 = mb * 128, n0 = nb * 128;

    const bf16* A = str ? A1 : A0;
    const bf16* W = str ? W1 : W0;
    const float* bia = str ? b1 : b0;
    bf16* C = str ? C1 : C0;

    const int lane = tid & 63, w = tid >> 6;
    const int wr = w >> 1, wc = w & 1;
    const int lr = lane & 15, lg = lane >> 4;
    const int srow = tid >> 2, scol = (tid & 3) * 8;

    const bf16* Ag = A + (size_t)(m0 + srow) * WK + scol;
    const bf16* Bg = W + (size_t)(n0 + srow) * WK + scol;

    f32x4 acc[4][4];
    const f32x4 zero = {0.f, 0.f, 0.f, 0.f};
#pragma unroll
    for (int mi = 0; mi < 4; ++mi)
#pragma unroll
        for (int nj = 0; nj < 4; ++nj) acc[mi][nj] = zero;

    auto stage = [&](int buf, int k0) {
        GL16(Ag + k0, &As[buf * 4096 + tid * 8]);
        GL16(Ag + (size_t)64 * WK + k0, &As[buf * 4096 + 2048 + tid * 8]);
        GL16(Bg + k0, &Bs[buf * 4096 + tid * 8]);
        GL16(Bg + (size_t)64 * WK + k0, &Bs[buf * 4096 + 2048 + tid * 8]);
    };
    auto compute = [&](int buf) {
        bf16x8 af[4], bfr[4];
#pragma unroll
        for (int mi = 0; mi < 4; ++mi)
            af[mi] = *reinterpret_cast<const bf16x8*>(&As[buf * 4096 + (wr * 64 + mi * 16 + lr) * 32 + lg * 8]);
#pragma unroll
        for (int nj = 0; nj < 4; ++nj)
            bfr[nj] = *reinterpret_cast<const bf16x8*>(&Bs[buf * 4096 + (wc * 64 + nj * 16 + lr) * 32 + lg * 8]);
#pragma unroll
        for (int mi = 0; mi < 4; ++mi)
#pragma unroll
            for (int nj = 0; nj < 4; ++nj)
                acc[mi][nj] = __builtin_amdgcn_mfma_f32_16x16x32_bf16(af[mi], bfr[nj], acc[mi][nj], 0, 0, 0);
    };

    const int NT = WK / 32;
    stage(0, 0);
    __syncthreads();
#pragma unroll
    for (int t = 0; t < NT - 1; ++t) {
        stage((t + 1) & 1, (t + 1) * 32);
        compute(t & 1);
        __syncthreads();
    }
    compute((NT - 1) & 1);

    __syncthreads();
#pragma unroll
    for (int nj = 0; nj < 4; ++nj) {
        int coll = wc * 64 + nj * 16 + lr;
        float bv = bia[n0 + coll];
#pragma unroll
        for (int mi = 0; mi < 4; ++mi)
#pragma unroll
            for (int i = 0; i < 4; ++i) {
                int rowl = wr * 64 + mi * 16 + lg * 4 + i;
                lds[rowl * 136 + coll] = (bf16)(acc[mi][nj][i] + bv);
            }
    }
    __syncthreads();
#pragma unroll
    for (int j = 0; j < 4; ++j) {
        int rowl = j * 32 + (tid >> 3);
        int gr = UNWIN ? unwin_idx(m0 + rowl) : (m0 + rowl);
#pragma unroll
        for (int h = 0; h < 2; ++h) {
            int coll = h * 64 + (tid & 7) * 8;
            *reinterpret_cast<bf16x8*>(C + (size_t)gr * 256 + n0 + coll) =
                *reinterpret_cast<const bf16x8*>(&lds[rowl * 136 + coll]);
        }
    }
}

// ---------------------------------------------------------------------------
// ln_fz (round-10 PASSING version, verbatim)
// ---------------------------------------------------------------------------
template<int RESF, int OUTF>
__global__ __launch_bounds__(256)
void ln_fz(const bf16* __restrict__ x0, const bf16* __restrict__ x1,
           const float* __restrict__ rf0, const float* __restrict__ rf1,
           const bf16* __restrict__ rb0, const bf16* __restrict__ rb1,
           const float* __restrict__ g0, const float* __restrict__ g1,
           const float* __restrict__ be0, const float* __restrict__ be1,
           float* __restrict__ of0, float* __restrict__ of1,
           bf16* __restrict__ ob0, bf16* __restrict__ ob1)
{
    const int bx = blockIdx.x;
    const int str = bx >> 14, b = bx & 16383;
    const bf16* x = str ? x1 : x0;
    const float* rf = str ? rf1 : rf0;
    const bf16* rb = str ? rb1 : rb0;
    const float* gamma = str ? g1 : g0;
    const float* beta = str ? be1 : be0;
    float* outf = str ? of1 : of0;
    bf16* outb = str ? ob1 : ob0;

    int row = b * 4 + (threadIdx.x >> 6);
    int lane = threadIdx.x & 63;
    size_t base = (size_t)row * 256 + lane * 4;
    bf16x4 xv = *reinterpret_cast<const bf16x4*>(x + base);
    float v[4];
    if (RESF) {
        float4 rv = *reinterpret_cast<const float4*>(rf + base);
        v[0] = rv.x + (float)xv[0];
        v[1] = rv.y + (float)xv[1];
        v[2] = rv.z + (float)xv[2];
        v[3] = rv.w + (float)xv[3];
    } else {
        bf16x4 rv = *reinterpret_cast<const bf16x4*>(rb + base);
        v[0] = (float)rv[0] + (float)xv[0];
        v[1] = (float)rv[1] + (float)xv[1];
        v[2] = (float)rv[2] + (float)xv[2];
        v[3] = (float)rv[3] + (float)xv[3];
    }
    float s = v[0] + v[1] + v[2] + v[3];
    float q = v[0] * v[0] + v[1] * v[1] + v[2] * v[2] + v[3] * v[3];
#pragma unroll
    for (int m = 1; m < 64; m <<= 1) {
        s += __shfl_xor(s, m);
        q += __shfl_xor(q, m);
    }
    float mean = s * (1.f / 256.f);
    float var = q * (1.f / 256.f) - mean * mean;
    float rstd = rsqrtf(var + 1e-5f);
    float4 gv = *reinterpret_cast<const float4*>(gamma + lane * 4);
    float4 bv = *reinterpret_cast<const float4*>(beta + lane * 4);
    float o[4];
    o[0] = (v[0] - mean) * rstd * gv.x + bv.x;
    o[1] = (v[1] - mean) * rstd * gv.y + bv.y;
    o[2] = (v[2] - mean) * rstd * gv.z + bv.z;
    o[3] = (v[3] - mean) * rstd * gv.w + bv.w;
    if (OUTF) {
        float4 ov; ov.x = o[0]; ov.y = o[1]; ov.z = o[2]; ov.w = o[3];
        *reinterpret_cast<float4*>(outf + base) = ov;
    } else {
        bf16x4 ob;
        ob[0] = (bf16)o[0]; ob[1] = (bf16)o[1]; ob[2] = (bf16)o[2]; ob[3] = (bf16)o[3];
        *reinterpret_cast<bf16x4*>(outb + base) = ob;
    }
}

// ---------------------------------------------------------------------------
// Merged attention (round-5 PASSING version, verbatim).
// ---------------------------------------------------------------------------
__global__ __launch_bounds__(256)
void attn_win2(const bf16* qA, const bf16* __restrict__ kA,
               const bf16* __restrict__ vA,
               const bf16* qB, const bf16* __restrict__ kB,
               const bf16* __restrict__ vB)
{
    __shared__ bf16 Ps[4][64][72];
    const int tid = threadIdx.x;
    const int wv = tid >> 6, lane = tid & 63;
    const int str = blockIdx.x >> 10, widx = blockIdx.x & 1023, head = wv;
    const int lr = lane & 15, lg = lane >> 4;
    const bf16* qbuf = str ? qB : qA;
    const bf16* kbuf = str ? kB : kA;
    const bf16* vtbuf = str ? vB : vA;
    bf16* obuf = const_cast<bf16*>(qbuf);
    const bf16* qb = qbuf + (size_t)widx * 64 * 256 + head * 64;
    const bf16* kb = kbuf + (size_t)widx * 64 * 256 + head * 64;
    const bf16* vb = vtbuf + (size_t)widx * 16384 + head * 64 * 64;

    const f32x4 zero = {0.f, 0.f, 0.f, 0.f};
    f32x4 sacc[4][4];
#pragma unroll
    for (int mi = 0; mi < 4; ++mi)
#pragma unroll
        for (int nj = 0; nj < 4; ++nj) sacc[mi][nj] = zero;

#pragma unroll
    for (int k0 = 0; k0 < 64; k0 += 32) {
        bf16x8 af[4], bfr[4];
#pragma unroll
        for (int mi = 0; mi < 4; ++mi)
            af[mi] = *reinterpret_cast<const bf16x8*>(qb + (size_t)(mi * 16 + lr) * 256 + k0 + lg * 8);
#pragma unroll
        for (int nj = 0; nj < 4; ++nj)
            bfr[nj] = *reinterpret_cast<const bf16x8*>(kb + (size_t)(nj * 16 + lr) * 256 + k0 + lg * 8);
#pragma unroll
        for (int mi = 0; mi < 4; ++mi)
#pragma unroll
            for (int nj = 0; nj < 4; ++nj)
                sacc[mi][nj] = __builtin_amdgcn_mfma_f32_16x16x32_bf16(af[mi], bfr[nj], sacc[mi][nj], 0, 0, 0);
    }

    const float c = 0.125f * 1.4426950408889634f;  // log2(e)/sqrt(dh)
    float rsum[4][4];
#pragma unroll
    for (int mi = 0; mi < 4; ++mi)
#pragma unroll
        for (int i = 0; i < 4; ++i) {
            float m = fmaxf(fmaxf(sacc[mi][0][i], sacc[mi][1][i]), fmaxf(sacc[mi][2][i], sacc[mi][3][i]));
            m = fmaxf(m, __shfl_xor(m, 1));
            m = fmaxf(m, __shfl_xor(m, 2));
            m = fmaxf(m, __shfl_xor(m, 4));
            m = fmaxf(m, __shfl_xor(m, 8));
#pragma unroll
            for (int nj = 0; nj < 4; ++nj)
                sacc[mi][nj][i] = exp2f((sacc[mi][nj][i] - m) * c);
            float s = sacc[mi][0][i] + sacc[mi][1][i] + sacc[mi][2][i] + sacc[mi][3][i];
            s += __shfl_xor(s, 1);
            s += __shfl_xor(s, 2);
            s += __shfl_xor(s, 4);
            s += __shfl_xor(s, 8);
            rsum[mi][i] = s;
        }

#pragma unroll
    for (int mi = 0; mi < 4; ++mi)
#pragma unroll
        for (int nj = 0; nj < 4; ++nj)
#pragma unroll
            for (int i = 0; i < 4; ++i)
                Ps[wv][mi * 16 + lg * 4 + i][nj * 16 + lr] = (bf16)sacc[mi][nj][i];

    f32x4 oacc[4][4];
#pragma unroll
    for (int mi = 0; mi < 4; ++mi)
#pragma unroll
        for (int nj = 0; nj < 4; ++nj) oacc[mi][nj] = zero;
#pragma unroll
    for (int k0 = 0; k0 < 64; k0 += 32) {
        bf16x8 af[4], bfr[4];
#pragma unroll
        for (int mi = 0; mi < 4; ++mi)
            af[mi] = *reinterpret_cast<const bf16x8*>(&Ps[wv][mi * 16 + lr][k0 + lg * 8]);
#pragma unroll
        for (int nj = 0; nj < 4; ++nj)
            bfr[nj] = *reinterpret_cast<const bf16x8*>(vb + (size_t)(nj * 16 + lr) * 64 + k0 + lg * 8);
#pragma unroll
        for (int mi = 0; mi < 4; ++mi)
#pragma unroll
            for (int nj = 0; nj < 4; ++nj)
                oacc[mi][nj] = __builtin_amdgcn_mfma_f32_16x16x32_bf16(af[mi], bfr[nj], oacc[mi][nj], 0, 0, 0);
    }
#pragma unroll
    for (int mi = 0; mi < 4; ++mi)
#pragma unroll
        for (int i = 0; i < 4; ++i) {
            float inv = 1.0f / rsum[mi][i];
            int row = mi * 16 + lg * 4 + i;
#pragma unroll
            for (int nj = 0; nj < 4; ++nj)
                obuf[((size_t)widx * 64 + row) * 256 + head * 64 + nj * 16 + lr] =
                    (bf16)(oacc[mi][nj][i] * inv);
        }
}

extern "C" void kernel_launch(void* const* d_in, const int* in_sizes, int n_in,
                              void* d_out, int out_size, void* d_ws, size_t ws_size,
                              hipStream_t stream)
{
    const float* feat_A       = (const float*)d_in[0];
    const float* feat_B       = (const float*)d_in[1];
    const float* pe           = (const float*)d_in[2];
    const float* qkv_w_A      = (const float*)d_in[3];
    const float* qkv_b_A      = (const float*)d_in[4];
    const float* out_w_A      = (const float*)d_in[5];
    const float* out_b_A      = (const float*)d_in[6];
    const float* norm_g_A     = (const float*)d_in[7];
    const float* norm_b_A     = (const float*)d_in[8];
    const float* ffn_norm_g_A = (const float*)d_in[9];
    const float* ffn_norm_b_A = (const float*)d_in[10];
    const float* ffn_w1_A     = (const float*)d_in[11];
    const float* ffn_b1_A     = (const float*)d_in[12];
    const float* ffn_w2_A     = (const float*)d_in[13];
    const float* ffn_b2_A     = (const float*)d_in[14];
    const float* qkv_w_B      = (const float*)d_in[15];
    const float* qkv_b_B      = (const float*)d_in[16];
    const float* out_w_B      = (const float*)d_in[17];
    const float* out_b_B      = (const float*)d_in[18];
    const float* norm_g_B     = (const float*)d_in[19];
    const float* norm_b_B     = (const float*)d_in[20];
    const float* ffn_norm_g_B = (const float*)d_in[21];
    const float* ffn_norm_b_B = (const float*)d_in[22];
    const float* ffn_w1_B     = (const float*)d_in[23];
    const float* ffn_b1_B     = (const float*)d_in[24];
    const float* ffn_w2_B     = (const float*)d_in[25];
    const float* ffn_b2_B     = (const float*)d_in[26];

    char* ws = (char*)d_ws;
    const size_t BFE = (size_t)NTOK * 256;      // 16,777,216 elems
    const size_t BFB = BFE * 2;                 // 33.55 MB per bf16 buffer

    // round-5 proven buffer plan (270.4 MB) + liveness reuse:
    bf16* Wb = (bf16*)ws;                       // 1M bf16 = 2 MB
    size_t off = 2u * 1024 * 1024;
    bf16* awA = (bf16*)(ws + off); off += BFB;
    bf16* awB = (bf16*)(ws + off); off += BFB;
    bf16* qA  = (bf16*)(ws + off); off += BFB;
    bf16* kA  = (bf16*)(ws + off); off += BFB;
    bf16* vA  = (bf16*)(ws + off); off += BFB;
    bf16* qB  = (bf16*)(ws + off); off += BFB;
    bf16* kB  = (bf16*)(ws + off); off += BFB;
    bf16* vB  = (bf16*)(ws + off); off += BFB;
    bf16* tb1A = kA;   // out-proj scratch (kA dead after attn)
    bf16* tb1B = vA;   // (vA dead after attn)
    bf16* y1A = kB;    // LN1 out (kB dead after attn)
    bf16* y1B = vB;    // (vB dead after attn)
    bf16* hbA = awA;   // FFN hidden, spans awA+awB
    bf16* hbB = kA;    // spans kA+vA (tb1 consumed by ln1 before gelu)
    bf16* tb2A = qA;   // FFN2 scratch (qA dead after out-proj)
    bf16* tb2B = qB;

    bf16* w_qkvA = Wb + 0;
    bf16* w_outA = Wb + 196608;
    bf16* w_f1A  = Wb + 262144;
    bf16* w_f2A  = Wb + 393216;
    bf16* w_qkvB = Wb + 524288;
    bf16* w_outB = Wb + 720896;
    bf16* w_f1B  = Wb + 786432;
    bf16* w_f2B  = Wb + 917504;

    cvt8<<<1024, 256, 0, stream>>>(qkv_w_A, out_w_A, ffn_w1_A, ffn_w2_A,
                                   qkv_w_B, out_w_B, ffn_w1_B, ffn_w2_B, Wb);
    prep_win<<<dim3(8192, 2), 256, 0, stream>>>(feat_A, feat_B, pe, awA, awB);

    gemm_qkv2<<<6144, 256, 0, stream>>>(awA, awB, w_qkvA, w_qkvB,
                                        qkv_b_A, qkv_b_B,
                                        qA, kA, vA, qB, kB, vB);

    attn_win2<<<2048, 256, 0, stream>>>(qA, kA, vA, qB, kB, vB);

    // out-proj both streams (unwin epilogue) -> tb1
    gemm_out<256, 1><<<2048, 256, 0, stream>>>(qA, qB, w_outA, w_outB,
                                               out_b_A, out_b_B, tb1A, tb1B);
    // LN1: y1 = LN(tb1 + feat) (bf16 out)
    ln_fz<1, 0><<<32768, 256, 0, stream>>>(tb1A, tb1B, feat_A, feat_B,
                                           nullptr, nullptr,
                                           norm_g_A, norm_g_B, norm_b_A, norm_b_B,
                                           nullptr, nullptr, y1A, y1B);
    // FFN1 both streams
    gemm_gelu<<<4096, 256, 0, stream>>>(y1A, y1B, w_f1A, w_f1B,
                                        ffn_b1_A, ffn_b1_B, hbA, hbB);
    // FFN2 both streams (linear epilogue) -> tb2
    gemm_out<512, 0><<<2048, 256, 0, stream>>>(hbA, hbB, w_f2A, w_f2B,
                                               ffn_b2_A, ffn_b2_B, tb2A, tb2B);
    // LN2: d_out = LN(tb2 + y1) (fp32 out)
    ln_fz<0, 1><<<32768, 256, 0, stream>>>(tb2A, tb2B, nullptr, nullptr,
                                           y1A, y1B,
                                           ffn_norm_g_A, ffn_norm_g_B,
                                           ffn_norm_b_A, ffn_norm_b_B,
                                           (float*)d_out, (float*)d_out + BFE,
                                           nullptr, nullptr);
}

// Round 16
// 449.630 us; speedup vs baseline: 1.0980x; 1.0106x over previous
//
#include <hip/hip_runtime.h>
#include <hip/hip_bf16.h>
#include <math.h>

typedef __bf16 bf16;
typedef __bf16 bf16x8 __attribute__((ext_vector_type(8)));
typedef __bf16 bf16x4 __attribute__((ext_vector_type(4)));
typedef float f32x4 __attribute__((ext_vector_type(4)));

#define NTOK 65536
#define DMODEL 256

// async global->LDS, 16B per lane; LDS dest = wave-uniform base + lane*16
#define GL16(g, l) __builtin_amdgcn_global_load_lds( \
    (const __attribute__((address_space(1))) void*)(g), \
    (__attribute__((address_space(3))) void*)(l), 16, 0, 0)

// window-order token m -> global token g (the _reverse mapping)
__device__ __forceinline__ int unwin_idx(int m) {
    int widx = m >> 6, t = m & 63;
    int b = widx >> 6, wl = widx & 63;
    return (b << 12) | (((wl >> 3) * 8 + (t >> 3)) << 6) | ((wl & 7) * 8 + (t & 7));
}

__device__ __forceinline__ float gelu_fast(float x) {
    float z = 0.7978845608f * (x + 0.044715f * x * x * x);
    float e = __expf(2.f * z);
    float t = (e - 1.f) / (e + 1.f);
    return 0.5f * x * (1.f + t);
}

// ---------------------------------------------------------------------------
// prep (round-5 PASSING version, verbatim)
// ---------------------------------------------------------------------------
__global__ __launch_bounds__(256)
void prep_win(const float* __restrict__ fA, const float* __restrict__ fB,
              const float* __restrict__ pe,
              bf16* __restrict__ awA, bf16* __restrict__ awB)
{
    const float* f = blockIdx.y ? fB : fA;
    bf16* aw = blockIdx.y ? awB : awA;
    int m = blockIdx.x * 8 + (threadIdx.x >> 5);
    int c = (threadIdx.x & 31) * 8;
    int g = unwin_idx(m), t = m & 63;
    const float4* fs = reinterpret_cast<const float4*>(f + (size_t)g * 256 + c);
    const float4* ps = reinterpret_cast<const float4*>(pe + t * 256 + c);
    float4 a0 = fs[0], a1 = fs[1], p0 = ps[0], p1 = ps[1];
    bf16x8 o;
    o[0] = (bf16)(a0.x + p0.x); o[1] = (bf16)(a0.y + p0.y);
    o[2] = (bf16)(a0.z + p0.z); o[3] = (bf16)(a0.w + p0.w);
    o[4] = (bf16)(a1.x + p1.x); o[5] = (bf16)(a1.y + p1.y);
    o[6] = (bf16)(a1.z + p1.z); o[7] = (bf16)(a1.w + p1.w);
    *reinterpret_cast<bf16x8*>(aw + (size_t)m * 256 + c) = o;
}

// ---------------------------------------------------------------------------
// weight convert (round-5 verbatim)
// ---------------------------------------------------------------------------
__global__ __launch_bounds__(256)
void cvt8(const float* __restrict__ s0, const float* __restrict__ s1,
          const float* __restrict__ s2, const float* __restrict__ s3,
          const float* __restrict__ s4, const float* __restrict__ s5,
          const float* __restrict__ s6, const float* __restrict__ s7,
          bf16* __restrict__ d)
{
    int idx = (blockIdx.x * 256 + threadIdx.x) * 4;
    const float* s; int off;
    if      (idx < 196608) { s = s0; off = 0; }
    else if (idx < 262144) { s = s1; off = 196608; }
    else if (idx < 393216) { s = s2; off = 262144; }
    else if (idx < 524288) { s = s3; off = 393216; }
    else if (idx < 720896) { s = s4; off = 524288; }
    else if (idx < 786432) { s = s5; off = 720896; }
    else if (idx < 917504) { s = s6; off = 786432; }
    else                   { s = s7; off = 917504; }
    float4 v = *reinterpret_cast<const float4*>(s + (idx - off));
    bf16x4 o; o[0] = (bf16)v.x; o[1] = (bf16)v.y; o[2] = (bf16)v.z; o[3] = (bf16)v.w;
    *reinterpret_cast<bf16x4*>(d + idx) = o;
}

// ---------------------------------------------------------------------------
// Merged QKV GEMM, both passes. K-loop = round-14 PASSING 2-buffer schedule,
// verbatim. NEW: seg0/1 epilogue uses the round-11-proven LDS-transpose
// coalesced store (union region 17408 elems); seg2 V-store unchanged.
// ---------------------------------------------------------------------------
__global__ __launch_bounds__(256, 4)
void gemm_qkv2(const bf16* __restrict__ awA, const bf16* __restrict__ awB,
               const bf16* __restrict__ wA, const bf16* __restrict__ wB,
               const float* __restrict__ bA, const float* __restrict__ bB,
               bf16* __restrict__ qA, bf16* __restrict__ kA, bf16* __restrict__ vA,
               bf16* __restrict__ qB, bf16* __restrict__ kB, bf16* __restrict__ vB)
{
    __shared__ bf16 lds[17408];      // staging [0,16384) ; epilogue tr [0,17408)
    bf16* As = lds;                  // As[buf] at buf*4096
    bf16* Bs = lds + 8192;           // Bs[buf] at buf*4096
    const int tid = threadIdx.x;
    const int bx = blockIdx.x;
    const int xcd = bx & 7, slot = bx >> 3;
    const int L = xcd * 768 + slot;
    const int mt = L / 6, nb = L - mt * 6;
    const int pass = mt >> 9, mb = mt & 511;
    const int seg = nb >> 1, nl0 = (nb & 1) * 128;
    const int m0 = mb * 128;

    const bf16* A = pass ? awB : awA;
    const bf16* Wf = (seg == 0) ? (pass ? wB : wA) : (pass ? wA : wB);
    const float* Bf = (seg == 0) ? (pass ? bB : bA) : (pass ? bA : bB);
    const bf16* W = Wf + (size_t)seg * 65536;
    const float* bia = Bf + seg * 256;
    bf16* qout = pass ? qB : qA;
    bf16* kout = pass ? kA : kB;
    bf16* vout = pass ? vA : vB;

    const int lane = tid & 63, w = tid >> 6;
    const int wr = w >> 1, wc = w & 1;
    const int lr = lane & 15, lg = lane >> 4;
    const int srow = tid >> 2, scol = (tid & 3) * 8;

    const bf16* Ag = A + (size_t)(m0 + srow) * 256 + scol;
    const bf16* Bg = W + (size_t)(nl0 + srow) * 256 + scol;

    f32x4 acc[4][4];
    const f32x4 zero = {0.f, 0.f, 0.f, 0.f};
#pragma unroll
    for (int mi = 0; mi < 4; ++mi)
#pragma unroll
        for (int nj = 0; nj < 4; ++nj) acc[mi][nj] = zero;

    auto stage = [&](int buf, int k0) {
        GL16(Ag + k0, &As[buf * 4096 + tid * 8]);
        GL16(Ag + 64 * 256 + k0, &As[buf * 4096 + 2048 + tid * 8]);
        GL16(Bg + k0, &Bs[buf * 4096 + tid * 8]);
        GL16(Bg + 64 * 256 + k0, &Bs[buf * 4096 + 2048 + tid * 8]);
    };
    auto compute = [&](int buf) {
        bf16x8 af[4], bfr[4];
#pragma unroll
        for (int mi = 0; mi < 4; ++mi)
            af[mi] = *reinterpret_cast<const bf16x8*>(&As[buf * 4096 + (wr * 64 + mi * 16 + lr) * 32 + lg * 8]);
#pragma unroll
        for (int nj = 0; nj < 4; ++nj)
            bfr[nj] = *reinterpret_cast<const bf16x8*>(&Bs[buf * 4096 + (wc * 64 + nj * 16 + lr) * 32 + lg * 8]);
#pragma unroll
        for (int mi = 0; mi < 4; ++mi)
#pragma unroll
            for (int nj = 0; nj < 4; ++nj)
                acc[mi][nj] = __builtin_amdgcn_mfma_f32_16x16x32_bf16(af[mi], bfr[nj], acc[mi][nj], 0, 0, 0);
    };

    stage(0, 0);
    __syncthreads();
#pragma unroll
    for (int t = 0; t < 7; ++t) {
        stage((t + 1) & 1, (t + 1) * 32);
        compute(t & 1);
        __syncthreads();
    }
    compute(1);

    if (seg == 2) {
        const int widx = mb * 2 + wr;
#pragma unroll
        for (int nj = 0; nj < 4; ++nj) {
            int cl = nl0 + wc * 64 + nj * 16 + lr;
            float bv = bia[cl];
#pragma unroll
            for (int mi = 0; mi < 4; ++mi) {
                bf16x4 o;
#pragma unroll
                for (int i = 0; i < 4; ++i) o[i] = (bf16)(acc[mi][nj][i] + bv);
                *reinterpret_cast<bf16x4*>(vout + ((size_t)widx * 256 + cl) * 64 + mi * 16 + lg * 4) = o;
            }
        }
    } else {
        bf16* out = (seg == 0) ? qout : kout;
        // round-11 proven LDS-transpose coalesced epilogue
        __syncthreads();
#pragma unroll
        for (int nj = 0; nj < 4; ++nj) {
            int coll = wc * 64 + nj * 16 + lr;
            float bv = bia[nl0 + coll];
#pragma unroll
            for (int mi = 0; mi < 4; ++mi)
#pragma unroll
                for (int i = 0; i < 4; ++i) {
                    int rowl = wr * 64 + mi * 16 + lg * 4 + i;
                    lds[rowl * 136 + coll] = (bf16)(acc[mi][nj][i] + bv);
                }
        }
        __syncthreads();
#pragma unroll
        for (int j = 0; j < 4; ++j) {
            int rowl = j * 32 + (tid >> 3);
#pragma unroll
            for (int h = 0; h < 2; ++h) {
                int coll = h * 64 + (tid & 7) * 8;
                *reinterpret_cast<bf16x8*>(out + (size_t)(m0 + rowl) * 256 + nl0 + coll) =
                    *reinterpret_cast<const bf16x8*>(&lds[rowl * 136 + coll]);
            }
        }
    }
}

// ---------------------------------------------------------------------------
// Merged FFN1 (round-11 PASSING version, verbatim): gelu + coalesced epilogue.
// ---------------------------------------------------------------------------
__global__ __launch_bounds__(256, 4)
void gemm_gelu(const bf16* __restrict__ y1A, const bf16* __restrict__ y1B,
               const bf16* __restrict__ wA, const bf16* __restrict__ wB,
               const float* __restrict__ bA, const float* __restrict__ bB,
               bf16* __restrict__ hbA, bf16* __restrict__ hbB)
{
    __shared__ bf16 lds[17408];
    bf16* As = lds;
    bf16* Bs = lds + 8192;
    const int tid = threadIdx.x;
    const int bx = blockIdx.x;
    const int xcd = bx & 7, slot = bx >> 3;
    const int L = xcd * 512 + slot;
    const int mt = L >> 2, nb = L & 3;
    const int str = mt >> 9, mb = mt & 511;
    const int m0 = mb * 128, n0 = nb * 128;

    const bf16* A = str ? y1B : y1A;
    const bf16* W = str ? wB : wA;
    const float* bia = str ? bB : bA;
    bf16* C = str ? hbB : hbA;

    const int lane = tid & 63, w = tid >> 6;
    const int wr = w >> 1, wc = w & 1;
    const int lr = lane & 15, lg = lane >> 4;
    const int srow = tid >> 2, scol = (tid & 3) * 8;

    const bf16* Ag = A + (size_t)(m0 + srow) * 256 + scol;
    const bf16* Bg = W + (size_t)(n0 + srow) * 256 + scol;

    f32x4 acc[4][4];
    const f32x4 zero = {0.f, 0.f, 0.f, 0.f};
#pragma unroll
    for (int mi = 0; mi < 4; ++mi)
#pragma unroll
        for (int nj = 0; nj < 4; ++nj) acc[mi][nj] = zero;

    auto stage = [&](int buf, int k0) {
        GL16(Ag + k0, &As[buf * 4096 + tid * 8]);
        GL16(Ag + 64 * 256 + k0, &As[buf * 4096 + 2048 + tid * 8]);
        GL16(Bg + k0, &Bs[buf * 4096 + tid * 8]);
        GL16(Bg + 64 * 256 + k0, &Bs[buf * 4096 + 2048 + tid * 8]);
    };
    auto compute = [&](int buf) {
        bf16x8 af[4], bfr[4];
#pragma unroll
        for (int mi = 0; mi < 4; ++mi)
            af[mi] = *reinterpret_cast<const bf16x8*>(&As[buf * 4096 + (wr * 64 + mi * 16 + lr) * 32 + lg * 8]);
#pragma unroll
        for (int nj = 0; nj < 4; ++nj)
            bfr[nj] = *reinterpret_cast<const bf16x8*>(&Bs[buf * 4096 + (wc * 64 + nj * 16 + lr) * 32 + lg * 8]);
#pragma unroll
        for (int mi = 0; mi < 4; ++mi)
#pragma unroll
            for (int nj = 0; nj < 4; ++nj)
                acc[mi][nj] = __builtin_amdgcn_mfma_f32_16x16x32_bf16(af[mi], bfr[nj], acc[mi][nj], 0, 0, 0);
    };

    stage(0, 0);
    __syncthreads();
#pragma unroll
    for (int t = 0; t < 7; ++t) {
        stage((t + 1) & 1, (t + 1) * 32);
        compute(t & 1);
        __syncthreads();
    }
    compute(1);

    __syncthreads();
#pragma unroll
    for (int nj = 0; nj < 4; ++nj) {
        int coll = wc * 64 + nj * 16 + lr;
        float bv = bia[n0 + coll];
#pragma unroll
        for (int mi = 0; mi < 4; ++mi)
#pragma unroll
            for (int i = 0; i < 4; ++i) {
                int rowl = wr * 64 + mi * 16 + lg * 4 + i;
                lds[rowl * 136 + coll] = (bf16)gelu_fast(acc[mi][nj][i] + bv);
            }
    }
    __syncthreads();
#pragma unroll
    for (int j = 0; j < 4; ++j)
#pragma unroll
        for (int h = 0; h < 2; ++h) {
            int rowl = j * 32 + (tid >> 3);
            int coll = h * 64 + (tid & 7) * 8;
            *reinterpret_cast<bf16x8*>(C + (size_t)(m0 + rowl) * 512 + n0 + coll) =
                *reinterpret_cast<const bf16x8*>(&lds[rowl * 136 + coll]);
        }
}

// ---------------------------------------------------------------------------
// gemm_out (round-11 PASSING version, verbatim).
// ---------------------------------------------------------------------------
template<int WK, int UNWIN>
__global__ __launch_bounds__(256, 4)
void gemm_out(const bf16* __restrict__ A0, const bf16* __restrict__ A1,
              const bf16* __restrict__ W0, const bf16* __restrict__ W1,
              const float* __restrict__ b0, const float* __restrict__ b1,
              bf16* __restrict__ C0, bf16* __restrict__ C1)
{
    __shared__ bf16 lds[17408];
    bf16* As = lds;
    bf16* Bs = lds + 8192;
    const int tid = threadIdx.x;
    const int bx = blockIdx.x;
    const int xcd = bx & 7, slot = bx >> 3;
    const int L = xcd * 256 + slot;
    const int mt = L >> 1, nb = L & 1;
    const int str = mt >> 9, mb = mt & 511;
    const int m0 = mb * 128, n0 = nb * 128;

    const bf16* A = str ? A1 : A0;
    const bf16* W = str ? W1 : W0;
    const float* bia = str ? b1 : b0;
    bf16* C = str ? C1 : C0;

    const int lane = tid & 63, w = tid >> 6;
    const int wr = w >> 1, wc = w & 1;
    const int lr = lane & 15, lg = lane >> 4;
    const int srow = tid >> 2, scol = (tid & 3) * 8;

    const bf16* Ag = A + (size_t)(m0 + srow) * WK + scol;
    const bf16* Bg = W + (size_t)(n0 + srow) * WK + scol;

    f32x4 acc[4][4];
    const f32x4 zero = {0.f, 0.f, 0.f, 0.f};
#pragma unroll
    for (int mi = 0; mi < 4; ++mi)
#pragma unroll
        for (int nj = 0; nj < 4; ++nj) acc[mi][nj] = zero;

    auto stage = [&](int buf, int k0) {
        GL16(Ag + k0, &As[buf * 4096 + tid * 8]);
        GL16(Ag + (size_t)64 * WK + k0, &As[buf * 4096 + 2048 + tid * 8]);
        GL16(Bg + k0, &Bs[buf * 4096 + tid * 8]);
        GL16(Bg + (size_t)64 * WK + k0, &Bs[buf * 4096 + 2048 + tid * 8]);
    };
    auto compute = [&](int buf) {
        bf16x8 af[4], bfr[4];
#pragma unroll
        for (int mi = 0; mi < 4; ++mi)
            af[mi] = *reinterpret_cast<const bf16x8*>(&As[buf * 4096 + (wr * 64 + mi * 16 + lr) * 32 + lg * 8]);
#pragma unroll
        for (int nj = 0; nj < 4; ++nj)
            bfr[nj] = *reinterpret_cast<const bf16x8*>(&Bs[buf * 4096 + (wc * 64 + nj * 16 + lr) * 32 + lg * 8]);
#pragma unroll
        for (int mi = 0; mi < 4; ++mi)
#pragma unroll
            for (int nj = 0; nj < 4; ++nj)
                acc[mi][nj] = __builtin_amdgcn_mfma_f32_16x16x32_bf16(af[mi], bfr[nj], acc[mi][nj], 0, 0, 0);
    };

    const int NT = WK / 32;
    stage(0, 0);
    __syncthreads();
#pragma unroll
    for (int t = 0; t < NT - 1; ++t) {
        stage((t + 1) & 1, (t + 1) * 32);
        compute(t & 1);
        __syncthreads();
    }
    compute((NT - 1) & 1);

    __syncthreads();
#pragma unroll
    for (int nj = 0; nj < 4; ++nj) {
        int coll = wc * 64 + nj * 16 + lr;
        float bv = bia[n0 + coll];
#pragma unroll
        for (int mi = 0; mi < 4; ++mi)
#pragma unroll
            for (int i = 0; i < 4; ++i) {
                int rowl = wr * 64 + mi * 16 + lg * 4 + i;
                lds[rowl * 136 + coll] = (bf16)(acc[mi][nj][i] + bv);
            }
    }
    __syncthreads();
#pragma unroll
    for (int j = 0; j < 4; ++j) {
        int rowl = j * 32 + (tid >> 3);
        int gr = UNWIN ? unwin_idx(m0 + rowl) : (m0 + rowl);
#pragma unroll
        for (int h = 0; h < 2; ++h) {
            int coll = h * 64 + (tid & 7) * 8;
            *reinterpret_cast<bf16x8*>(C + (size_t)gr * 256 + n0 + coll) =
                *reinterpret_cast<const bf16x8*>(&lds[rowl * 136 + coll]);
        }
    }
}

// ---------------------------------------------------------------------------
// ln_fz (round-10 PASSING version, verbatim)
// ---------------------------------------------------------------------------
template<int RESF, int OUTF>
__global__ __launch_bounds__(256)
void ln_fz(const bf16* __restrict__ x0, const bf16* __restrict__ x1,
           const float* __restrict__ rf0, const float* __restrict__ rf1,
           const bf16* __restrict__ rb0, const bf16* __restrict__ rb1,
           const float* __restrict__ g0, const float* __restrict__ g1,
           const float* __restrict__ be0, const float* __restrict__ be1,
           float* __restrict__ of0, float* __restrict__ of1,
           bf16* __restrict__ ob0, bf16* __restrict__ ob1)
{
    const int bx = blockIdx.x;
    const int str = bx >> 14, b = bx & 16383;
    const bf16* x = str ? x1 : x0;
    const float* rf = str ? rf1 : rf0;
    const bf16* rb = str ? rb1 : rb0;
    const float* gamma = str ? g1 : g0;
    const float* beta = str ? be1 : be0;
    float* outf = str ? of1 : of0;
    bf16* outb = str ? ob1 : ob0;

    int row = b * 4 + (threadIdx.x >> 6);
    int lane = threadIdx.x & 63;
    size_t base = (size_t)row * 256 + lane * 4;
    bf16x4 xv = *reinterpret_cast<const bf16x4*>(x + base);
    float v[4];
    if (RESF) {
        float4 rv = *reinterpret_cast<const float4*>(rf + base);
        v[0] = rv.x + (float)xv[0];
        v[1] = rv.y + (float)xv[1];
        v[2] = rv.z + (float)xv[2];
        v[3] = rv.w + (float)xv[3];
    } else {
        bf16x4 rv = *reinterpret_cast<const bf16x4*>(rb + base);
        v[0] = (float)rv[0] + (float)xv[0];
        v[1] = (float)rv[1] + (float)xv[1];
        v[2] = (float)rv[2] + (float)xv[2];
        v[3] = (float)rv[3] + (float)xv[3];
    }
    float s = v[0] + v[1] + v[2] + v[3];
    float q = v[0] * v[0] + v[1] * v[1] + v[2] * v[2] + v[3] * v[3];
#pragma unroll
    for (int m = 1; m < 64; m <<= 1) {
        s += __shfl_xor(s, m);
        q += __shfl_xor(q, m);
    }
    float mean = s * (1.f / 256.f);
    float var = q * (1.f / 256.f) - mean * mean;
    float rstd = rsqrtf(var + 1e-5f);
    float4 gv = *reinterpret_cast<const float4*>(gamma + lane * 4);
    float4 bv = *reinterpret_cast<const float4*>(beta + lane * 4);
    float o[4];
    o[0] = (v[0] - mean) * rstd * gv.x + bv.x;
    o[1] = (v[1] - mean) * rstd * gv.y + bv.y;
    o[2] = (v[2] - mean) * rstd * gv.z + bv.z;
    o[3] = (v[3] - mean) * rstd * gv.w + bv.w;
    if (OUTF) {
        float4 ov; ov.x = o[0]; ov.y = o[1]; ov.z = o[2]; ov.w = o[3];
        *reinterpret_cast<float4*>(outf + base) = ov;
    } else {
        bf16x4 ob;
        ob[0] = (bf16)o[0]; ob[1] = (bf16)o[1]; ob[2] = (bf16)o[2]; ob[3] = (bf16)o[3];
        *reinterpret_cast<bf16x4*>(outb + base) = ob;
    }
}

// ---------------------------------------------------------------------------
// Merged attention (round-5 PASSING version, verbatim).
// ---------------------------------------------------------------------------
__global__ __launch_bounds__(256)
void attn_win2(const bf16* qA, const bf16* __restrict__ kA,
               const bf16* __restrict__ vA,
               const bf16* qB, const bf16* __restrict__ kB,
               const bf16* __restrict__ vB)
{
    __shared__ bf16 Ps[4][64][72];
    const int tid = threadIdx.x;
    const int wv = tid >> 6, lane = tid & 63;
    const int str = blockIdx.x >> 10, widx = blockIdx.x & 1023, head = wv;
    const int lr = lane & 15, lg = lane >> 4;
    const bf16* qbuf = str ? qB : qA;
    const bf16* kbuf = str ? kB : kA;
    const bf16* vtbuf = str ? vB : vA;
    bf16* obuf = const_cast<bf16*>(qbuf);
    const bf16* qb = qbuf + (size_t)widx * 64 * 256 + head * 64;
    const bf16* kb = kbuf + (size_t)widx * 64 * 256 + head * 64;
    const bf16* vb = vtbuf + (size_t)widx * 16384 + head * 64 * 64;

    const f32x4 zero = {0.f, 0.f, 0.f, 0.f};
    f32x4 sacc[4][4];
#pragma unroll
    for (int mi = 0; mi < 4; ++mi)
#pragma unroll
        for (int nj = 0; nj < 4; ++nj) sacc[mi][nj] = zero;

#pragma unroll
    for (int k0 = 0; k0 < 64; k0 += 32) {
        bf16x8 af[4], bfr[4];
#pragma unroll
        for (int mi = 0; mi < 4; ++mi)
            af[mi] = *reinterpret_cast<const bf16x8*>(qb + (size_t)(mi * 16 + lr) * 256 + k0 + lg * 8);
#pragma unroll
        for (int nj = 0; nj < 4; ++nj)
            bfr[nj] = *reinterpret_cast<const bf16x8*>(kb + (size_t)(nj * 16 + lr) * 256 + k0 + lg * 8);
#pragma unroll
        for (int mi = 0; mi < 4; ++mi)
#pragma unroll
            for (int nj = 0; nj < 4; ++nj)
                sacc[mi][nj] = __builtin_amdgcn_mfma_f32_16x16x32_bf16(af[mi], bfr[nj], sacc[mi][nj], 0, 0, 0);
    }

    const float c = 0.125f * 1.4426950408889634f;  // log2(e)/sqrt(dh)
    float rsum[4][4];
#pragma unroll
    for (int mi = 0; mi < 4; ++mi)
#pragma unroll
        for (int i = 0; i < 4; ++i) {
            float m = fmaxf(fmaxf(sacc[mi][0][i], sacc[mi][1][i]), fmaxf(sacc[mi][2][i], sacc[mi][3][i]));
            m = fmaxf(m, __shfl_xor(m, 1));
            m = fmaxf(m, __shfl_xor(m, 2));
            m = fmaxf(m, __shfl_xor(m, 4));
            m = fmaxf(m, __shfl_xor(m, 8));
#pragma unroll
            for (int nj = 0; nj < 4; ++nj)
                sacc[mi][nj][i] = exp2f((sacc[mi][nj][i] - m) * c);
            float s = sacc[mi][0][i] + sacc[mi][1][i] + sacc[mi][2][i] + sacc[mi][3][i];
            s += __shfl_xor(s, 1);
            s += __shfl_xor(s, 2);
            s += __shfl_xor(s, 4);
            s += __shfl_xor(s, 8);
            rsum[mi][i] = s;
        }

#pragma unroll
    for (int mi = 0; mi < 4; ++mi)
#pragma unroll
        for (int nj = 0; nj < 4; ++nj)
#pragma unroll
            for (int i = 0; i < 4; ++i)
                Ps[wv][mi * 16 + lg * 4 + i][nj * 16 + lr] = (bf16)sacc[mi][nj][i];

    f32x4 oacc[4][4];
#pragma unroll
    for (int mi = 0; mi < 4; ++mi)
#pragma unroll
        for (int nj = 0; nj < 4; ++nj) oacc[mi][nj] = zero;
#pragma unroll
    for (int k0 = 0; k0 < 64; k0 += 32) {
        bf16x8 af[4], bfr[4];
#pragma unroll
        for (int mi = 0; mi < 4; ++mi)
            af[mi] = *reinterpret_cast<const bf16x8*>(&Ps[wv][mi * 16 + lr][k0 + lg * 8]);
#pragma unroll
        for (int nj = 0; nj < 4; ++nj)
            bfr[nj] = *reinterpret_cast<const bf16x8*>(vb + (size_t)(nj * 16 + lr) * 64 + k0 + lg * 8);
#pragma unroll
        for (int mi = 0; mi < 4; ++mi)
#pragma unroll
            for (int nj = 0; nj < 4; ++nj)
                oacc[mi][nj] = __builtin_amdgcn_mfma_f32_16x16x32_bf16(af[mi], bfr[nj], oacc[mi][nj], 0, 0, 0);
    }
#pragma unroll
    for (int mi = 0; mi < 4; ++mi)
#pragma unroll
        for (int i = 0; i < 4; ++i) {
            float inv = 1.0f / rsum[mi][i];
            int row = mi * 16 + lg * 4 + i;
#pragma unroll
            for (int nj = 0; nj < 4; ++nj)
                obuf[((size_t)widx * 64 + row) * 256 + head * 64 + nj * 16 + lr] =
                    (bf16)(oacc[mi][nj][i] * inv);
        }
}

extern "C" void kernel_launch(void* const* d_in, const int* in_sizes, int n_in,
                              void* d_out, int out_size, void* d_ws, size_t ws_size,
                              hipStream_t stream)
{
    const float* feat_A       = (const float*)d_in[0];
    const float* feat_B       = (const float*)d_in[1];
    const float* pe           = (const float*)d_in[2];
    const float* qkv_w_A      = (const float*)d_in[3];
    const float* qkv_b_A      = (const float*)d_in[4];
    const float* out_w_A      = (const float*)d_in[5];
    const float* out_b_A      = (const float*)d_in[6];
    const float* norm_g_A     = (const float*)d_in[7];
    const float* norm_b_A     = (const float*)d_in[8];
    const float* ffn_norm_g_A = (const float*)d_in[9];
    const float* ffn_norm_b_A = (const float*)d_in[10];
    const float* ffn_w1_A     = (const float*)d_in[11];
    const float* ffn_b1_A     = (const float*)d_in[12];
    const float* ffn_w2_A     = (const float*)d_in[13];
    const float* ffn_b2_A     = (const float*)d_in[14];
    const float* qkv_w_B      = (const float*)d_in[15];
    const float* qkv_b_B      = (const float*)d_in[16];
    const float* out_w_B      = (const float*)d_in[17];
    const float* out_b_B      = (const float*)d_in[18];
    const float* norm_g_B     = (const float*)d_in[19];
    const float* norm_b_B     = (const float*)d_in[20];
    const float* ffn_norm_g_B = (const float*)d_in[21];
    const float* ffn_norm_b_B = (const float*)d_in[22];
    const float* ffn_w1_B     = (const float*)d_in[23];
    const float* ffn_b1_B     = (const float*)d_in[24];
    const float* ffn_w2_B     = (const float*)d_in[25];
    const float* ffn_b2_B     = (const float*)d_in[26];

    char* ws = (char*)d_ws;
    const size_t BFE = (size_t)NTOK * 256;      // 16,777,216 elems
    const size_t BFB = BFE * 2;                 // 33.55 MB per bf16 buffer

    // round-5 proven buffer plan (270.4 MB) + liveness reuse:
    bf16* Wb = (bf16*)ws;                       // 1M bf16 = 2 MB
    size_t off = 2u * 1024 * 1024;
    bf16* awA = (bf16*)(ws + off); off += BFB;
    bf16* awB = (bf16*)(ws + off); off += BFB;
    bf16* qA  = (bf16*)(ws + off); off += BFB;
    bf16* kA  = (bf16*)(ws + off); off += BFB;
    bf16* vA  = (bf16*)(ws + off); off += BFB;
    bf16* qB  = (bf16*)(ws + off); off += BFB;
    bf16* kB  = (bf16*)(ws + off); off += BFB;
    bf16* vB  = (bf16*)(ws + off); off += BFB;
    bf16* tb1A = kA;   // out-proj scratch (kA dead after attn)
    bf16* tb1B = vA;   // (vA dead after attn)
    bf16* y1A = kB;    // LN1 out (kB dead after attn)
    bf16* y1B = vB;    // (vB dead after attn)
    bf16* hbA = awA;   // FFN hidden, spans awA+awB
    bf16* hbB = kA;    // spans kA+vA (tb1 consumed by ln1 before gelu)
    bf16* tb2A = qA;   // FFN2 scratch (qA dead after out-proj)
    bf16* tb2B = qB;

    bf16* w_qkvA = Wb + 0;
    bf16* w_outA = Wb + 196608;
    bf16* w_f1A  = Wb + 262144;
    bf16* w_f2A  = Wb + 393216;
    bf16* w_qkvB = Wb + 524288;
    bf16* w_outB = Wb + 720896;
    bf16* w_f1B  = Wb + 786432;
    bf16* w_f2B  = Wb + 917504;

    cvt8<<<1024, 256, 0, stream>>>(qkv_w_A, out_w_A, ffn_w1_A, ffn_w2_A,
                                   qkv_w_B, out_w_B, ffn_w1_B, ffn_w2_B, Wb);
    prep_win<<<dim3(8192, 2), 256, 0, stream>>>(feat_A, feat_B, pe, awA, awB);

    gemm_qkv2<<<6144, 256, 0, stream>>>(awA, awB, w_qkvA, w_qkvB,
                                        qkv_b_A, qkv_b_B,
                                        qA, kA, vA, qB, kB, vB);

    attn_win2<<<2048, 256, 0, stream>>>(qA, kA, vA, qB, kB, vB);

    // out-proj both streams (unwin epilogue) -> tb1
    gemm_out<256, 1><<<2048, 256, 0, stream>>>(qA, qB, w_outA, w_outB,
                                               out_b_A, out_b_B, tb1A, tb1B);
    // LN1: y1 = LN(tb1 + feat) (bf16 out)
    ln_fz<1, 0><<<32768, 256, 0, stream>>>(tb1A, tb1B, feat_A, feat_B,
                                           nullptr, nullptr,
                                           norm_g_A, norm_g_B, norm_b_A, norm_b_B,
                                           nullptr, nullptr, y1A, y1B);
    // FFN1 both streams
    gemm_gelu<<<4096, 256, 0, stream>>>(y1A, y1B, w_f1A, w_f1B,
                                        ffn_b1_A, ffn_b1_B, hbA, hbB);
    // FFN2 both streams (linear epilogue) -> tb2
    gemm_out<512, 0><<<2048, 256, 0, stream>>>(hbA, hbB, w_f2A, w_f2B,
                                               ffn_b2_A, ffn_b2_B, tb2A, tb2B);
    // LN2: d_out = LN(tb2 + y1) (fp32 out)
    ln_fz<0, 1><<<32768, 256, 0, stream>>>(tb2A, tb2B, nullptr, nullptr,
                                           y1A, y1B,
                                           ffn_norm_g_A, ffn_norm_g_B,
                                           ffn_norm_b_A, ffn_norm_b_B,
                                           (float*)d_out, (float*)d_out + BFE,
                                           nullptr, nullptr);
}